// Round 1
// baseline (3394.060 us; speedup 1.0000x reference)
//
#include <hip/hip_runtime.h>
#include <hip/hip_bf16.h>

#define BB 512
#define NA 58
#define LAT 64
#define HID 128
#define AF 10
#define NL 2
#define NN (BB*NA)      // 29696
#define NE (NN*16)      // 475136
#define TE 16
#define NB 8

struct CvtDesc {
    const void* src[24];
    float*      dst[24];
    int         len[24];
};

__device__ __forceinline__ float siluf(float x) {
    return x / (1.0f + __expf(-x));
}

// ---------------------------------------------------------------------------
// Detect storage formats: flags[0] = float tensors are bf16, flags[1] = edge_index is int64
__global__ void k_detect(const unsigned short* __restrict__ z16,
                         const unsigned int* __restrict__ e32,
                         int* __restrict__ flags) {
    __shared__ int sbf, si64;
    if (threadIdx.x == 0) { sbf = 0; si64 = 0; }
    __syncthreads();
    int c1 = 0, c2 = 0;
    for (int i = threadIdx.x; i < 1024; i += 256) {
        unsigned short v = z16[2*i];          // bf16: element 2i; f32: low mantissa bits of elt i
        int e = (v >> 7) & 0xFF;
        if (e >= 100 && e <= 140) c1++;       // plausible bf16 exponent for ~N(0,1) data
        if (e32[2*i + 1] == 0u) c2++;         // int64: high words all zero
    }
    atomicAdd(&sbf, c1);
    atomicAdd(&si64, c2);
    __syncthreads();
    if (threadIdx.x == 0) {
        flags[0] = (sbf  > 600) ? 1 : 0;
        flags[1] = (si64 > 600) ? 1 : 0;
    }
}

// Normalize all float inputs to f32 in workspace (bf16->f32 or f32 copy)
__global__ void k_convert(CvtDesc d, const int* __restrict__ flags) {
    int a = blockIdx.y;
    int i = blockIdx.x * blockDim.x + threadIdx.x;
    int n = d.len[a];
    if (i >= n) return;
    if (flags[0]) {
        d.dst[a][i] = __bfloat162float(((const __hip_bfloat16*)d.src[a])[i]);
    } else {
        d.dst[a][i] = ((const float*)d.src[a])[i];
    }
}

// ---------------------------------------------------------------------------
// hz[b] = z[b] @ latent_w + latent_b          grid: BB blocks x 128
__global__ void k_hz(const float* __restrict__ z, const float* __restrict__ lw,
                     const float* __restrict__ lb, float* __restrict__ hz) {
    __shared__ float zs[LAT];
    int b = blockIdx.x;
    int c = threadIdx.x;
    if (c < LAT) zs[c] = z[b*LAT + c];
    __syncthreads();
    float acc = lb[c];
    #pragma unroll
    for (int k = 0; k < LAT; ++k) acc += zs[k] * lw[k*HID + c];
    hz[b*HID + c] = acc;
}

// h[n] = hz[n/NA] + atom_types[n] @ atom_w + atom_b      grid: NN blocks x 128
__global__ void k_init_h(const float* __restrict__ hz, const float* __restrict__ at,
                         const float* __restrict__ aw, const float* __restrict__ ab,
                         float* __restrict__ h) {
    __shared__ float ats[AF];
    int n = blockIdx.x;
    int c = threadIdx.x;
    int b = n / NA;
    if (c < AF) ats[c] = at[n*AF + c];
    __syncthreads();
    float acc = hz[b*HID + c] + ab[c];
    #pragma unroll
    for (int f = 0; f < AF; ++f) acc += ats[f] * aw[f*HID + c];
    h[(long)n*HID + c] = acc;
}

__global__ void k_init_pos(const float* __restrict__ ic, float* __restrict__ pos) {
    int i = blockIdx.x * blockDim.x + threadIdx.x;
    if (i >= NN*3) return;
    int n = i / 3, d = i - n*3;
    int a = n % NA;
    pos[i] = ic[a*3 + d];
}

__global__ void k_zero(float* __restrict__ agg, float* __restrict__ upd,
                       float* __restrict__ deg) {
    int i = blockIdx.x * blockDim.x + threadIdx.x;
    if (i < NN*HID) agg[i] = 0.f;
    if (i < NN*3)   upd[i] = 0.f;
    if (i < NN)     deg[i] = 0.f;
}

// ---------------------------------------------------------------------------
// Fused edge kernel: 16 edges / block of 256 threads.
__global__ __launch_bounds__(256) void k_edge(
    const float* __restrict__ h, const float* __restrict__ pos,
    const int* __restrict__ eidx, const int* __restrict__ flags,
    const float* __restrict__ w1, const float* __restrict__ b1,
    const float* __restrict__ w2, const float* __restrict__ b2,
    const float* __restrict__ cw1, const float* __restrict__ cb1,
    const float* __restrict__ cw2,
    float* __restrict__ agg, float* __restrict__ upd, float* __restrict__ deg)
{
    __shared__ float ef[TE][260];     // [xi(128) | xj(128) | d2], padded row
    __shared__ float t1[TE][HID];
    __shared__ float mm[TE][HID];
    __shared__ float c1[TE][HID];
    __shared__ int   rI[TE], cI[TE];
    __shared__ float relS[TE][3];

    const int tid = threadIdx.x;
    const long eb = (long)blockIdx.x * TE;

    if (tid < TE) {
        int is64 = flags[1];
        long ge = eb + tid;
        int r  = eidx[is64 ? 2*ge : ge];
        long gc = ge + NE;
        int cn = eidx[is64 ? 2*gc : gc];
        rI[tid] = r; cI[tid] = cn;
        float rx = pos[r*3+0] - pos[cn*3+0];
        float ry = pos[r*3+1] - pos[cn*3+1];
        float rz = pos[r*3+2] - pos[cn*3+2];
        relS[tid][0] = rx; relS[tid][1] = ry; relS[tid][2] = rz;
        float d2 = rx*rx + ry*ry + rz*rz;
        d2 = fminf(fmaxf(d2, 1e-6f), 1e6f);
        ef[tid][256] = d2;
    }
    __syncthreads();

    {   // gather xi / xj (coalesced 512B rows)
        const int half = tid >> 7;
        const int j = tid & 127;
        #pragma unroll
        for (int e = 0; e < TE; ++e) {
            int node = half ? cI[e] : rI[e];
            ef[e][half*HID + j] = h[(long)node*HID + j];
        }
    }
    __syncthreads();

    const int c = tid & 127;
    const int g = tid >> 7;     // edge group: [g*8, g*8+8)
    float acc[8];

    // stage 1: t1 = silu(ef @ w1 + b1), K = 257
    {
        float bias = b1[c];
        #pragma unroll
        for (int i = 0; i < 8; ++i) acc[i] = bias;
        for (int k4 = 0; k4 < 64; ++k4) {
            int k = k4*4;
            float wa = w1[(k+0)*HID + c];
            float wb = w1[(k+1)*HID + c];
            float wc = w1[(k+2)*HID + c];
            float wd = w1[(k+3)*HID + c];
            #pragma unroll
            for (int i = 0; i < 8; ++i) {
                float4 v = *(const float4*)&ef[g*8+i][k];
                acc[i] += v.x*wa + v.y*wb + v.z*wc + v.w*wd;
            }
        }
        float we = w1[256*HID + c];
        #pragma unroll
        for (int i = 0; i < 8; ++i) {
            acc[i] += ef[g*8+i][256] * we;
            t1[g*8+i][c] = siluf(acc[i]);
        }
    }
    __syncthreads();

    // stage 2: m = silu(t1 @ w2 + b2); scatter-add into agg
    {
        float bias = b2[c];
        #pragma unroll
        for (int i = 0; i < 8; ++i) acc[i] = bias;
        for (int k4 = 0; k4 < 32; ++k4) {
            int k = k4*4;
            float wa = w2[(k+0)*HID + c];
            float wb = w2[(k+1)*HID + c];
            float wc = w2[(k+2)*HID + c];
            float wd = w2[(k+3)*HID + c];
            #pragma unroll
            for (int i = 0; i < 8; ++i) {
                float4 v = *(const float4*)&t1[g*8+i][k];
                acc[i] += v.x*wa + v.y*wb + v.z*wc + v.w*wd;
            }
        }
        #pragma unroll
        for (int i = 0; i < 8; ++i) {
            float mv = siluf(acc[i]);
            mm[g*8+i][c] = mv;
            atomicAdd(&agg[(long)rI[g*8+i]*HID + c], mv);
        }
    }
    __syncthreads();

    // stage 3: c1 = silu(mm @ cw1 + cb1)
    {
        float bias = cb1[c];
        #pragma unroll
        for (int i = 0; i < 8; ++i) acc[i] = bias;
        for (int k4 = 0; k4 < 32; ++k4) {
            int k = k4*4;
            float wa = cw1[(k+0)*HID + c];
            float wb = cw1[(k+1)*HID + c];
            float wc = cw1[(k+2)*HID + c];
            float wd = cw1[(k+3)*HID + c];
            #pragma unroll
            for (int i = 0; i < 8; ++i) {
                float4 v = *(const float4*)&mm[g*8+i][k];
                acc[i] += v.x*wa + v.y*wb + v.z*wc + v.w*wd;
            }
        }
        #pragma unroll
        for (int i = 0; i < 8; ++i) c1[g*8+i][c] = siluf(acc[i]);
    }
    __syncthreads();

    // stage 4: cw = clip(c1 @ cw2, -1, 1); scatter-add cw*rel into upd, deg++
    {
        int e = tid >> 4;
        int part = tid & 15;
        float s = 0.f;
        #pragma unroll
        for (int k = 0; k < 8; ++k) {
            int kk = part*8 + k;
            s += c1[e][kk] * cw2[kk];
        }
        s += __shfl_xor(s, 8);
        s += __shfl_xor(s, 4);
        s += __shfl_xor(s, 2);
        s += __shfl_xor(s, 1);
        if (part == 0) {
            float cwv = fminf(fmaxf(s, -1.f), 1.f);
            int r = rI[e];
            atomicAdd(&upd[r*3+0], cwv*relS[e][0]);
            atomicAdd(&upd[r*3+1], cwv*relS[e][1]);
            atomicAdd(&upd[r*3+2], cwv*relS[e][2]);
            atomicAdd(&deg[r], 1.0f);
        }
    }
}

// ---------------------------------------------------------------------------
// Node update: hn = LN(silu([h|agg]@w1+b1)@w2+b2); pos += upd/(deg+1e-6)
__global__ __launch_bounds__(128) void k_node(
    float* __restrict__ h, const float* __restrict__ agg,
    const float* __restrict__ w1, const float* __restrict__ b1,
    const float* __restrict__ w2, const float* __restrict__ b2,
    const float* __restrict__ lg, const float* __restrict__ lb,
    float* __restrict__ pos, const float* __restrict__ upd,
    const float* __restrict__ deg)
{
    __shared__ float x[NB][256];
    __shared__ float t[NB][HID];
    __shared__ float rsum[2][NB], rsq[2][NB];
    const int tid = threadIdx.x;         // 128
    const int n0 = blockIdx.x * NB;

    #pragma unroll
    for (int i = 0; i < NB; ++i) {
        x[i][tid]       = h[(long)(n0+i)*HID + tid];
        x[i][HID + tid] = agg[(long)(n0+i)*HID + tid];
    }
    __syncthreads();

    float acc[NB];
    float bias = b1[tid];
    #pragma unroll
    for (int i = 0; i < NB; ++i) acc[i] = bias;
    for (int k4 = 0; k4 < 64; ++k4) {
        int k = k4*4;
        float wa = w1[(k+0)*HID + tid];
        float wb = w1[(k+1)*HID + tid];
        float wc = w1[(k+2)*HID + tid];
        float wd = w1[(k+3)*HID + tid];
        #pragma unroll
        for (int i = 0; i < NB; ++i) {
            float4 v = *(const float4*)&x[i][k];
            acc[i] += v.x*wa + v.y*wb + v.z*wc + v.w*wd;
        }
    }
    #pragma unroll
    for (int i = 0; i < NB; ++i) t[i][tid] = siluf(acc[i]);
    __syncthreads();

    #pragma unroll
    for (int i = 0; i < NB; ++i) acc[i] = b2[tid];
    for (int k4 = 0; k4 < 32; ++k4) {
        int k = k4*4;
        float wa = w2[(k+0)*HID + tid];
        float wb = w2[(k+1)*HID + tid];
        float wc = w2[(k+2)*HID + tid];
        float wd = w2[(k+3)*HID + tid];
        #pragma unroll
        for (int i = 0; i < NB; ++i) {
            float4 v = *(const float4*)&t[i][k];
            acc[i] += v.x*wa + v.y*wb + v.z*wc + v.w*wd;
        }
    }

    // LayerNorm across the 128 channels (2 waves)
    const int wv = tid >> 6, ln = tid & 63;
    #pragma unroll
    for (int i = 0; i < NB; ++i) {
        float s = acc[i], q = acc[i]*acc[i];
        #pragma unroll
        for (int off = 32; off > 0; off >>= 1) {
            s += __shfl_xor(s, off);
            q += __shfl_xor(q, off);
        }
        if (ln == 0) { rsum[wv][i] = s; rsq[wv][i] = q; }
    }
    __syncthreads();
    float g = lg[tid], bb = lb[tid];
    #pragma unroll
    for (int i = 0; i < NB; ++i) {
        float s = rsum[0][i] + rsq[0][i]*0.f + rsum[1][i];
        float q = rsq[0][i] + rsq[1][i];
        float mu = s * (1.0f/HID);
        float var = q * (1.0f/HID) - mu*mu;
        float r = rsqrtf(var + 1e-5f);
        h[(long)(n0+i)*HID + tid] = (acc[i] - mu) * r * g + bb;
    }
    if (tid < NB*3) {
        int i = tid / 3, d = tid - i*3;
        int n = n0 + i;
        pos[n*3+d] += upd[n*3+d] / (deg[n] + 1e-6f);
    }
}

// ---------------------------------------------------------------------------
// Head: out = pos + silu(h@w1+b1)@w2+b2     4 nodes / block of 256
__global__ void k_head(const float* __restrict__ h, const float* __restrict__ pos,
                       const float* __restrict__ w1, const float* __restrict__ b1,
                       const float* __restrict__ w2, const float* __restrict__ b2,
                       void* __restrict__ out, const int* __restrict__ flags)
{
    __shared__ float hs[4][HID];
    __shared__ float t[4][64];
    const int tid = threadIdx.x;     // 256
    const int n0 = blockIdx.x * 4;
    for (int i = tid; i < 4*HID; i += 256) hs[i >> 7][i & 127] = h[(long)n0*HID + i];
    __syncthreads();
    const int s = tid >> 6, c = tid & 63;
    float acc = b1[c];
    for (int k4 = 0; k4 < 32; ++k4) {
        int k = k4*4;
        float wa = w1[(k+0)*64 + c];
        float wb = w1[(k+1)*64 + c];
        float wc = w1[(k+2)*64 + c];
        float wd = w1[(k+3)*64 + c];
        float4 v = *(const float4*)&hs[s][k];
        acc += v.x*wa + v.y*wb + v.z*wc + v.w*wd;
    }
    t[s][c] = siluf(acc);
    __syncthreads();
    if (c < 3) {
        float a2 = b2[c];
        #pragma unroll
        for (int k = 0; k < 64; ++k) a2 += t[s][k] * w2[k*3 + c];
        int n = n0 + s;
        float v = pos[n*3+c] + a2;
        if (flags[0]) ((__hip_bfloat16*)out)[n*3+c] = __float2bfloat16(v);
        else          ((float*)out)[n*3+c] = v;
    }
}

// ---------------------------------------------------------------------------
extern "C" void kernel_launch(void* const* d_in, const int* in_sizes, int n_in,
                              void* d_out, int out_size, void* d_ws, size_t ws_size,
                              hipStream_t stream)
{
    (void)in_sizes; (void)n_in; (void)out_size; (void)ws_size;

    int* flags = (int*)d_ws;
    float* base = (float*)d_ws;
    size_t off = 64;
    auto alloc = [&](size_t n) { float* p = base + off; off += (n + 63) & ~63ull; return p; };

    static const int aidx[24] = {0,1,3,4,5,6,7,8,9,10,11,12,13,14,15,16,17,18,19,20,21,22,23,24};
    static const int alen[24] = {
        BB*LAT, NN*AF, NA*3, LAT*HID, HID, AF*HID, HID,
        NL*257*HID, NL*HID, NL*HID*HID, NL*HID,
        NL*256*HID, NL*HID, NL*HID*HID, NL*HID,
        NL*HID*HID, NL*HID, NL*HID, NL*HID, NL*HID,
        HID*64, 64, 64*3, 3
    };
    CvtDesc cd;
    float* fp[24];
    for (int a = 0; a < 24; ++a) {
        fp[a] = alloc((size_t)alen[a]);
        cd.src[a] = d_in[aidx[a]];
        cd.dst[a] = fp[a];
        cd.len[a] = alen[a];
    }
    float* h   = alloc((size_t)NN*HID);
    float* agg = alloc((size_t)NN*HID);
    float* hz  = alloc((size_t)BB*HID);
    float* pos = alloc((size_t)NN*3);
    float* upd = alloc((size_t)NN*3);
    float* deg = alloc((size_t)NN);
    const int* eidx = (const int*)d_in[2];

    k_detect<<<1, 256, 0, stream>>>((const unsigned short*)d_in[0],
                                    (const unsigned int*)d_in[2], flags);
    k_convert<<<dim3((NN*AF + 255)/256, 24), 256, 0, stream>>>(cd, flags);
    k_hz<<<BB, HID, 0, stream>>>(fp[0], fp[3], fp[4], hz);
    k_init_h<<<NN, HID, 0, stream>>>(hz, fp[1], fp[5], fp[6], h);
    k_init_pos<<<(NN*3 + 255)/256, 256, 0, stream>>>(fp[2], pos);

    for (int l = 0; l < NL; ++l) {
        k_zero<<<(NN*HID + 255)/256, 256, 0, stream>>>(agg, upd, deg);
        k_edge<<<NE/TE, 256, 0, stream>>>(h, pos, eidx, flags,
            fp[7] + (size_t)l*257*HID, fp[8] + (size_t)l*HID,
            fp[9] + (size_t)l*HID*HID, fp[10] + (size_t)l*HID,
            fp[15] + (size_t)l*HID*HID, fp[16] + (size_t)l*HID,
            fp[17] + (size_t)l*HID,
            agg, upd, deg);
        k_node<<<NN/NB, HID, 0, stream>>>(h, agg,
            fp[11] + (size_t)l*256*HID, fp[12] + (size_t)l*HID,
            fp[13] + (size_t)l*HID*HID, fp[14] + (size_t)l*HID,
            fp[18] + (size_t)l*HID, fp[19] + (size_t)l*HID,
            pos, upd, deg);
    }
    k_head<<<NN/4, 256, 0, stream>>>(h, pos, fp[20], fp[21], fp[22], fp[23],
                                     d_out, flags);
}

// Round 2
// 1058.704 us; speedup vs baseline: 3.2059x; 3.2059x over previous
//
#include <hip/hip_runtime.h>
#include <hip/hip_bf16.h>

#define BB 512
#define NA 58
#define LAT 64
#define HID 128
#define AF 10
#define NL 2
#define NN (BB*NA)      // 29696
#define NE (NN*16)      // 475136
#define ET 64           // edges per MFMA block
#define NB 8

typedef __attribute__((ext_vector_type(8))) short s8;
typedef __attribute__((ext_vector_type(4))) float f4;

struct CvtDesc {
    const void* src[24];
    float*      dst[24];
    int         len[24];
};

__device__ __forceinline__ float siluf(float x) {
    return x / (1.0f + __expf(-x));
}

__device__ __forceinline__ short f2b(float x) {
    __hip_bfloat16 b = __float2bfloat16(x);
    return *(short*)&b;
}

// ---------------------------------------------------------------------------
__global__ void k_detect(const unsigned short* __restrict__ z16,
                         const unsigned int* __restrict__ e32,
                         int* __restrict__ flags) {
    __shared__ int sbf, si64;
    if (threadIdx.x == 0) { sbf = 0; si64 = 0; }
    __syncthreads();
    int c1 = 0, c2 = 0;
    for (int i = threadIdx.x; i < 1024; i += 256) {
        unsigned short v = z16[2*i];
        int e = (v >> 7) & 0xFF;
        if (e >= 100 && e <= 140) c1++;
        if (e32[2*i + 1] == 0u) c2++;
    }
    atomicAdd(&sbf, c1);
    atomicAdd(&si64, c2);
    __syncthreads();
    if (threadIdx.x == 0) {
        flags[0] = (sbf  > 600) ? 1 : 0;
        flags[1] = (si64 > 600) ? 1 : 0;
    }
}

__global__ void k_convert(CvtDesc d, const int* __restrict__ flags) {
    int a = blockIdx.y;
    int i = blockIdx.x * blockDim.x + threadIdx.x;
    int n = d.len[a];
    if (i >= n) return;
    if (flags[0]) {
        d.dst[a][i] = __bfloat162float(((const __hip_bfloat16*)d.src[a])[i]);
    } else {
        d.dst[a][i] = ((const float*)d.src[a])[i];
    }
}

// Pack f32 weight [K][128] into bf16 B-fragment order:
// out[((nt*(K/32)+kc)*64 + l)*8 + j] = w[kc*32+(l>>4)*8+j][nt*16+(l&15)]
__global__ void k_pack(const float* __restrict__ w, short* __restrict__ o, int K) {
    int idx = blockIdx.x * 256 + threadIdx.x;
    int total = 128 * K;
    if (idx >= total) return;
    int j  = idx & 7;
    int l  = (idx >> 3) & 63;
    int rest = idx >> 9;
    int KC = K >> 5;
    int kc = rest % KC;
    int nt = rest / KC;
    int n = nt*16 + (l & 15);
    int k = kc*32 + (l >> 4)*8 + j;
    o[idx] = f2b(w[k*128 + n]);
}

__global__ void k_h2b(const float* __restrict__ h, short* __restrict__ hb) {
    int i = blockIdx.x * 256 + threadIdx.x;
    if (i < NN*HID) hb[i] = f2b(h[i]);
}

// ---------------------------------------------------------------------------
__global__ void k_hz(const float* __restrict__ z, const float* __restrict__ lw,
                     const float* __restrict__ lb, float* __restrict__ hz) {
    __shared__ float zs[LAT];
    int b = blockIdx.x;
    int c = threadIdx.x;
    if (c < LAT) zs[c] = z[b*LAT + c];
    __syncthreads();
    float acc = lb[c];
    #pragma unroll
    for (int k = 0; k < LAT; ++k) acc += zs[k] * lw[k*HID + c];
    hz[b*HID + c] = acc;
}

__global__ void k_init_h(const float* __restrict__ hz, const float* __restrict__ at,
                         const float* __restrict__ aw, const float* __restrict__ ab,
                         float* __restrict__ h) {
    __shared__ float ats[AF];
    int n = blockIdx.x;
    int c = threadIdx.x;
    int b = n / NA;
    if (c < AF) ats[c] = at[n*AF + c];
    __syncthreads();
    float acc = hz[b*HID + c] + ab[c];
    #pragma unroll
    for (int f = 0; f < AF; ++f) acc += ats[f] * aw[f*HID + c];
    h[(long)n*HID + c] = acc;
}

__global__ void k_init_pos(const float* __restrict__ ic, float* __restrict__ pos) {
    int i = blockIdx.x * blockDim.x + threadIdx.x;
    if (i >= NN*3) return;
    int n = i / 3, d = i - n*3;
    int a = n % NA;
    pos[i] = ic[a*3 + d];
}

__global__ void k_zero(float* __restrict__ agg, float* __restrict__ upd,
                       float* __restrict__ deg) {
    int i = blockIdx.x * blockDim.x + threadIdx.x;
    if (i < NN*HID) agg[i] = 0.f;
    if (i < NN*3)   upd[i] = 0.f;
    if (i < NN)     deg[i] = 0.f;
}

// ---------------------------------------------------------------------------
// MFMA edge kernel: 64 edges / block, 4 waves, wave = M64 x N32.
// ef LDS stride 264 (16B-aligned, bank-balanced); t1/mm stride 144.
__global__ __launch_bounds__(256) void k_edge_mfma(
    const short* __restrict__ hb, const float* __restrict__ pos,
    const int* __restrict__ eidx, const int* __restrict__ flags,
    const short* __restrict__ w1p, const float* __restrict__ w1last,
    const float* __restrict__ b1,
    const short* __restrict__ w2p, const float* __restrict__ b2,
    const short* __restrict__ c1p, const float* __restrict__ cb1,
    const float* __restrict__ cw2,
    float* __restrict__ agg, float* __restrict__ upd, float* __restrict__ deg)
{
    __shared__ short ef[ET][264];       // xi|xj bf16; later aliased by mm
    __shared__ short t1[ET][144];
    __shared__ int   rIs[ET], cIs[ET];
    __shared__ float relS[ET][3];
    __shared__ float d2s[ET];
    __shared__ float sred[ET];
    short (*mm)[144] = (short (*)[144])&ef[0][0];   // ef dead after stage1

    const int tid = threadIdx.x;
    const long eb = (long)blockIdx.x * ET;

    if (tid < ET) {
        int is64 = flags[1];
        long ge = eb + tid;
        int r  = eidx[is64 ? 2*ge : ge];
        long gc = ge + NE;
        int cn = eidx[is64 ? 2*gc : gc];
        rIs[tid] = r; cIs[tid] = cn;
        float rx = pos[r*3+0] - pos[cn*3+0];
        float ry = pos[r*3+1] - pos[cn*3+1];
        float rz = pos[r*3+2] - pos[cn*3+2];
        relS[tid][0] = rx; relS[tid][1] = ry; relS[tid][2] = rz;
        float d2 = rx*rx + ry*ry + rz*rz;
        d2s[tid] = fminf(fmaxf(d2, 1e-6f), 1e6f);
        sred[tid] = 0.f;
    }
    __syncthreads();

    // gather xi/xj rows (bf16, 16B chunks; 2048 chunks / 256 thr)
    #pragma unroll
    for (int it = 0; it < 8; ++it) {
        int idx = it*256 + tid;
        int e = idx >> 5, c16 = idx & 31;
        int node = (c16 & 16) ? cIs[e] : rIs[e];
        int q = c16 & 15;
        int4 v = *(const int4*)(hb + (long)node*HID + q*8);
        *(int4*)&ef[e][c16*8] = v;
    }
    __syncthreads();

    const int l = tid & 63, w = tid >> 6;
    const int l16 = l & 15, quad = l >> 4;
    const int nt0 = 2*w, nt1 = 2*w + 1;
    const int c0 = nt0*16 + l16, c1c = nt1*16 + l16;

    // ---- stage 1: t1 = silu(ef @ w1 + b1), K=256 via MFMA + f32 d2 term
    {
        f4 acc[4][2];
        #pragma unroll
        for (int mt = 0; mt < 4; ++mt) { acc[mt][0] = (f4)0.f; acc[mt][1] = (f4)0.f; }
        #pragma unroll
        for (int kc = 0; kc < 8; ++kc) {
            s8 b0 = *(const s8*)(w1p + (((size_t)nt0*8 + kc)*64 + l)*8);
            s8 b1f = *(const s8*)(w1p + (((size_t)nt1*8 + kc)*64 + l)*8);
            #pragma unroll
            for (int mt = 0; mt < 4; ++mt) {
                s8 a = *(const s8*)&ef[mt*16 + l16][kc*32 + quad*8];
                acc[mt][0] = __builtin_amdgcn_mfma_f32_16x16x32_bf16(a, b0, acc[mt][0], 0, 0, 0);
                acc[mt][1] = __builtin_amdgcn_mfma_f32_16x16x32_bf16(a, b1f, acc[mt][1], 0, 0, 0);
            }
        }
        float bia0 = b1[c0], bia1 = b1[c1c];
        float wl0 = w1last[c0], wl1 = w1last[c1c];
        __syncthreads();   // all ef reads done before t1 writes race nothing; keep order
        #pragma unroll
        for (int mt = 0; mt < 4; ++mt) {
            #pragma unroll
            for (int i = 0; i < 4; ++i) {
                int row = mt*16 + quad*4 + i;
                float d2 = d2s[row];
                t1[row][c0]  = f2b(siluf(acc[mt][0][i] + bia0 + d2*wl0));
                t1[row][c1c] = f2b(siluf(acc[mt][1][i] + bia1 + d2*wl1));
            }
        }
    }
    __syncthreads();

    // ---- stage 2: m = silu(t1 @ w2 + b2) -> mm (bf16) + atomic agg (f32)
    {
        f4 acc[4][2];
        #pragma unroll
        for (int mt = 0; mt < 4; ++mt) { acc[mt][0] = (f4)0.f; acc[mt][1] = (f4)0.f; }
        #pragma unroll
        for (int kc = 0; kc < 4; ++kc) {
            s8 b0 = *(const s8*)(w2p + (((size_t)nt0*4 + kc)*64 + l)*8);
            s8 b1f = *(const s8*)(w2p + (((size_t)nt1*4 + kc)*64 + l)*8);
            #pragma unroll
            for (int mt = 0; mt < 4; ++mt) {
                s8 a = *(const s8*)&t1[mt*16 + l16][kc*32 + quad*8];
                acc[mt][0] = __builtin_amdgcn_mfma_f32_16x16x32_bf16(a, b0, acc[mt][0], 0, 0, 0);
                acc[mt][1] = __builtin_amdgcn_mfma_f32_16x16x32_bf16(a, b1f, acc[mt][1], 0, 0, 0);
            }
        }
        float bia0 = b2[c0], bia1 = b2[c1c];
        __syncthreads();   // ensure nobody still reads ef (mm aliases it)
        #pragma unroll
        for (int mt = 0; mt < 4; ++mt) {
            #pragma unroll
            for (int i = 0; i < 4; ++i) {
                int row = mt*16 + quad*4 + i;
                float m0 = siluf(acc[mt][0][i] + bia0);
                float m1 = siluf(acc[mt][1][i] + bia1);
                mm[row][c0]  = f2b(m0);
                mm[row][c1c] = f2b(m1);
                long node = rIs[row];
                atomicAdd(&agg[node*HID + c0],  m0);
                atomicAdd(&agg[node*HID + c1c], m1);
            }
        }
    }
    __syncthreads();

    // ---- stage 3: c1 = silu(mm @ cw1 + cb1); stage 4: dot with cw2, reduce
    {
        f4 acc[4][2];
        #pragma unroll
        for (int mt = 0; mt < 4; ++mt) { acc[mt][0] = (f4)0.f; acc[mt][1] = (f4)0.f; }
        #pragma unroll
        for (int kc = 0; kc < 4; ++kc) {
            s8 b0 = *(const s8*)(c1p + (((size_t)nt0*4 + kc)*64 + l)*8);
            s8 b1f = *(const s8*)(c1p + (((size_t)nt1*4 + kc)*64 + l)*8);
            #pragma unroll
            for (int mt = 0; mt < 4; ++mt) {
                s8 a = *(const s8*)&mm[mt*16 + l16][kc*32 + quad*8];
                acc[mt][0] = __builtin_amdgcn_mfma_f32_16x16x32_bf16(a, b0, acc[mt][0], 0, 0, 0);
                acc[mt][1] = __builtin_amdgcn_mfma_f32_16x16x32_bf16(a, b1f, acc[mt][1], 0, 0, 0);
            }
        }
        float bia0 = cb1[c0], bia1 = cb1[c1c];
        float cw0 = cw2[c0], cw1v = cw2[c1c];
        #pragma unroll
        for (int mt = 0; mt < 4; ++mt) {
            #pragma unroll
            for (int i = 0; i < 4; ++i) {
                float p = siluf(acc[mt][0][i] + bia0) * cw0
                        + siluf(acc[mt][1][i] + bia1) * cw1v;
                p += __shfl_xor(p, 1);
                p += __shfl_xor(p, 2);
                p += __shfl_xor(p, 4);
                p += __shfl_xor(p, 8);
                if (l16 == 0) {
                    int row = mt*16 + quad*4 + i;
                    atomicAdd(&sred[row], p);
                }
            }
        }
    }
    __syncthreads();

    if (tid < ET) {
        float cwv = fminf(fmaxf(sred[tid], -1.f), 1.f);
        int r = rIs[tid];
        atomicAdd(&upd[r*3+0], cwv*relS[tid][0]);
        atomicAdd(&upd[r*3+1], cwv*relS[tid][1]);
        atomicAdd(&upd[r*3+2], cwv*relS[tid][2]);
        atomicAdd(&deg[r], 1.0f);
    }
}

// ---------------------------------------------------------------------------
__global__ __launch_bounds__(128) void k_node(
    float* __restrict__ h, const float* __restrict__ agg,
    const float* __restrict__ w1, const float* __restrict__ b1,
    const float* __restrict__ w2, const float* __restrict__ b2,
    const float* __restrict__ lg, const float* __restrict__ lb,
    float* __restrict__ pos, const float* __restrict__ upd,
    const float* __restrict__ deg)
{
    __shared__ float x[NB][256];
    __shared__ float t[NB][HID];
    __shared__ float rsum[2][NB], rsq[2][NB];
    const int tid = threadIdx.x;
    const int n0 = blockIdx.x * NB;

    #pragma unroll
    for (int i = 0; i < NB; ++i) {
        x[i][tid]       = h[(long)(n0+i)*HID + tid];
        x[i][HID + tid] = agg[(long)(n0+i)*HID + tid];
    }
    __syncthreads();

    float acc[NB];
    float bias = b1[tid];
    #pragma unroll
    for (int i = 0; i < NB; ++i) acc[i] = bias;
    for (int k4 = 0; k4 < 64; ++k4) {
        int k = k4*4;
        float wa = w1[(k+0)*HID + tid];
        float wb = w1[(k+1)*HID + tid];
        float wc = w1[(k+2)*HID + tid];
        float wd = w1[(k+3)*HID + tid];
        #pragma unroll
        for (int i = 0; i < NB; ++i) {
            float4 v = *(const float4*)&x[i][k];
            acc[i] += v.x*wa + v.y*wb + v.z*wc + v.w*wd;
        }
    }
    #pragma unroll
    for (int i = 0; i < NB; ++i) t[i][tid] = siluf(acc[i]);
    __syncthreads();

    #pragma unroll
    for (int i = 0; i < NB; ++i) acc[i] = b2[tid];
    for (int k4 = 0; k4 < 32; ++k4) {
        int k = k4*4;
        float wa = w2[(k+0)*HID + tid];
        float wb = w2[(k+1)*HID + tid];
        float wc = w2[(k+2)*HID + tid];
        float wd = w2[(k+3)*HID + tid];
        #pragma unroll
        for (int i = 0; i < NB; ++i) {
            float4 v = *(const float4*)&t[i][k];
            acc[i] += v.x*wa + v.y*wb + v.z*wc + v.w*wd;
        }
    }

    const int wv = tid >> 6, ln = tid & 63;
    #pragma unroll
    for (int i = 0; i < NB; ++i) {
        float s = acc[i], q = acc[i]*acc[i];
        #pragma unroll
        for (int off = 32; off > 0; off >>= 1) {
            s += __shfl_xor(s, off);
            q += __shfl_xor(q, off);
        }
        if (ln == 0) { rsum[wv][i] = s; rsq[wv][i] = q; }
    }
    __syncthreads();
    float g = lg[tid], bb = lb[tid];
    #pragma unroll
    for (int i = 0; i < NB; ++i) {
        float s = rsum[0][i] + rsum[1][i];
        float q = rsq[0][i] + rsq[1][i];
        float mu = s * (1.0f/HID);
        float var = q * (1.0f/HID) - mu*mu;
        float r = rsqrtf(var + 1e-5f);
        h[(long)(n0+i)*HID + tid] = (acc[i] - mu) * r * g + bb;
    }
    if (tid < NB*3) {
        int i = tid / 3, d = tid - i*3;
        int n = n0 + i;
        pos[n*3+d] += upd[n*3+d] / (deg[n] + 1e-6f);
    }
}

// ---------------------------------------------------------------------------
__global__ void k_head(const float* __restrict__ h, const float* __restrict__ pos,
                       const float* __restrict__ w1, const float* __restrict__ b1,
                       const float* __restrict__ w2, const float* __restrict__ b2,
                       void* __restrict__ out, const int* __restrict__ flags)
{
    __shared__ float hs[4][HID];
    __shared__ float t[4][64];
    const int tid = threadIdx.x;
    const int n0 = blockIdx.x * 4;
    for (int i = tid; i < 4*HID; i += 256) hs[i >> 7][i & 127] = h[(long)n0*HID + i];
    __syncthreads();
    const int s = tid >> 6, c = tid & 63;
    float acc = b1[c];
    for (int k4 = 0; k4 < 32; ++k4) {
        int k = k4*4;
        float wa = w1[(k+0)*64 + c];
        float wb = w1[(k+1)*64 + c];
        float wc = w1[(k+2)*64 + c];
        float wd = w1[(k+3)*64 + c];
        float4 v = *(const float4*)&hs[s][k];
        acc += v.x*wa + v.y*wb + v.z*wc + v.w*wd;
    }
    t[s][c] = siluf(acc);
    __syncthreads();
    if (c < 3) {
        float a2 = b2[c];
        #pragma unroll
        for (int k = 0; k < 64; ++k) a2 += t[s][k] * w2[k*3 + c];
        int n = n0 + s;
        float v = pos[n*3+c] + a2;
        if (flags[0]) ((__hip_bfloat16*)out)[n*3+c] = __float2bfloat16(v);
        else          ((float*)out)[n*3+c] = v;
    }
}

// ---------------------------------------------------------------------------
extern "C" void kernel_launch(void* const* d_in, const int* in_sizes, int n_in,
                              void* d_out, int out_size, void* d_ws, size_t ws_size,
                              hipStream_t stream)
{
    (void)in_sizes; (void)n_in; (void)out_size; (void)ws_size;

    int* flags = (int*)d_ws;
    float* base = (float*)d_ws;
    size_t off = 64;
    auto alloc = [&](size_t n) { float* p = base + off; off += (n + 63) & ~63ull; return p; };

    static const int aidx[24] = {0,1,3,4,5,6,7,8,9,10,11,12,13,14,15,16,17,18,19,20,21,22,23,24};
    static const int alen[24] = {
        BB*LAT, NN*AF, NA*3, LAT*HID, HID, AF*HID, HID,
        NL*257*HID, NL*HID, NL*HID*HID, NL*HID,
        NL*256*HID, NL*HID, NL*HID*HID, NL*HID,
        NL*HID*HID, NL*HID, NL*HID, NL*HID, NL*HID,
        HID*64, 64, 64*3, 3
    };
    CvtDesc cd;
    float* fp[24];
    for (int a = 0; a < 24; ++a) {
        fp[a] = alloc((size_t)alen[a]);
        cd.src[a] = d_in[aidx[a]];
        cd.dst[a] = fp[a];
        cd.len[a] = alen[a];
    }
    float* h   = alloc((size_t)NN*HID);
    float* agg = alloc((size_t)NN*HID);
    float* hz  = alloc((size_t)BB*HID);
    float* pos = alloc((size_t)NN*3);
    float* upd = alloc((size_t)NN*3);
    float* deg = alloc((size_t)NN);
    short* hb  = (short*)alloc((size_t)NN*HID/2);
    short* w1p = (short*)alloc((size_t)NL*128*256/2*2);  // NL*32768 shorts
    short* w2p = (short*)alloc((size_t)NL*128*128/2*2);
    short* c1p = (short*)alloc((size_t)NL*128*128/2*2);
    const int* eidx = (const int*)d_in[2];

    k_detect<<<1, 256, 0, stream>>>((const unsigned short*)d_in[0],
                                    (const unsigned int*)d_in[2], flags);
    k_convert<<<dim3((NN*AF + 255)/256, 24), 256, 0, stream>>>(cd, flags);

    for (int l = 0; l < NL; ++l) {
        k_pack<<<128, 256, 0, stream>>>(fp[7]  + (size_t)l*257*HID, w1p + (size_t)l*32768, 256);
        k_pack<<<64,  256, 0, stream>>>(fp[9]  + (size_t)l*HID*HID, w2p + (size_t)l*16384, 128);
        k_pack<<<64,  256, 0, stream>>>(fp[15] + (size_t)l*HID*HID, c1p + (size_t)l*16384, 128);
    }

    k_hz<<<BB, HID, 0, stream>>>(fp[0], fp[3], fp[4], hz);
    k_init_h<<<NN, HID, 0, stream>>>(hz, fp[1], fp[5], fp[6], h);
    k_init_pos<<<(NN*3 + 255)/256, 256, 0, stream>>>(fp[2], pos);

    for (int l = 0; l < NL; ++l) {
        k_zero<<<(NN*HID + 255)/256, 256, 0, stream>>>(agg, upd, deg);
        k_h2b<<<(NN*HID + 255)/256, 256, 0, stream>>>(h, hb);
        k_edge_mfma<<<NE/ET, 256, 0, stream>>>(hb, pos, eidx, flags,
            w1p + (size_t)l*32768,
            fp[7] + (size_t)l*257*HID + 256*HID,
            fp[8] + (size_t)l*HID,
            w2p + (size_t)l*16384, fp[10] + (size_t)l*HID,
            c1p + (size_t)l*16384, fp[16] + (size_t)l*HID,
            fp[17] + (size_t)l*HID,
            agg, upd, deg);
        k_node<<<NN/NB, HID, 0, stream>>>(h, agg,
            fp[11] + (size_t)l*256*HID, fp[12] + (size_t)l*HID,
            fp[13] + (size_t)l*HID*HID, fp[14] + (size_t)l*HID,
            fp[18] + (size_t)l*HID, fp[19] + (size_t)l*HID,
            pos, upd, deg);
    }
    k_head<<<NN/4, 256, 0, stream>>>(h, pos, fp[20], fp[21], fp[22], fp[23],
                                     d_out, flags);
}

// Round 3
// 975.000 us; speedup vs baseline: 3.4811x; 1.0859x over previous
//
#include <hip/hip_runtime.h>
#include <hip/hip_bf16.h>

#define BB 512
#define NA 58
#define LAT 64
#define HID 128
#define AF 10
#define NL 2
#define NN (BB*NA)      // 29696
#define NE (NN*16)      // 475136
#define ET 64           // edges per MFMA block

typedef __attribute__((ext_vector_type(8))) short s8;
typedef __attribute__((ext_vector_type(4))) float f4;

struct CvtDesc {
    const void* src[24];
    float*      dst[24];
    int         len[24];
};

__device__ __forceinline__ float siluf(float x) {
    return x / (1.0f + __expf(-x));
}

__device__ __forceinline__ short f2b(float x) {
    __hip_bfloat16 b = __float2bfloat16(x);
    return *(short*)&b;
}

// ---------------------------------------------------------------------------
__global__ void k_detect(const unsigned short* __restrict__ z16,
                         const unsigned int* __restrict__ e32,
                         int* __restrict__ flags) {
    __shared__ int sbf, si64;
    if (threadIdx.x == 0) { sbf = 0; si64 = 0; }
    __syncthreads();
    int c1 = 0, c2 = 0;
    for (int i = threadIdx.x; i < 1024; i += 256) {
        unsigned short v = z16[2*i];
        int e = (v >> 7) & 0xFF;
        if (e >= 100 && e <= 140) c1++;
        if (e32[2*i + 1] == 0u) c2++;
    }
    atomicAdd(&sbf, c1);
    atomicAdd(&si64, c2);
    __syncthreads();
    if (threadIdx.x == 0) {
        flags[0] = (sbf  > 600) ? 1 : 0;
        flags[1] = (si64 > 600) ? 1 : 0;
    }
}

__global__ void k_convert(CvtDesc d, const int* __restrict__ flags) {
    int a = blockIdx.y;
    int i = blockIdx.x * blockDim.x + threadIdx.x;
    int n = d.len[a];
    if (i >= n) return;
    if (flags[0]) {
        d.dst[a][i] = __bfloat162float(((const __hip_bfloat16*)d.src[a])[i]);
    } else {
        d.dst[a][i] = ((const float*)d.src[a])[i];
    }
}

// Pack f32 weight [K][128] into bf16 B-fragment order
__global__ void k_pack(const float* __restrict__ w, short* __restrict__ o, int K) {
    int idx = blockIdx.x * 256 + threadIdx.x;
    int total = 128 * K;
    if (idx >= total) return;
    int j  = idx & 7;
    int l  = (idx >> 3) & 63;
    int rest = idx >> 9;
    int KC = K >> 5;
    int kc = rest % KC;
    int nt = rest / KC;
    int n = nt*16 + (l & 15);
    int k = kc*32 + (l >> 4)*8 + j;
    o[idx] = f2b(w[k*128 + n]);
}

__global__ void k_h2b(const float* __restrict__ h, short* __restrict__ hb) {
    int i = blockIdx.x * 256 + threadIdx.x;
    if (i < NN*HID) hb[i] = f2b(h[i]);
}

// ---------------------------------------------------------------------------
// counting sort of edges by row
__global__ void k_zero_cnt(int* __restrict__ cnt) {
    int i = blockIdx.x * 256 + threadIdx.x;
    if (i < NN) cnt[i] = 0;
}

__global__ void k_hist(const int* __restrict__ eidx, const int* __restrict__ flags,
                       int* __restrict__ cnt) {
    int e = blockIdx.x * 256 + threadIdx.x;
    if (e >= NE) return;
    int is64 = flags[1];
    int r = eidx[is64 ? 2*(long)e : (long)e];
    atomicAdd(&cnt[r], 1);
}

__global__ __launch_bounds__(1024) void k_scan(const int* __restrict__ cnt,
                                               int* __restrict__ rowStart,
                                               int* __restrict__ cursor) {
    __shared__ int part[1024];
    int t = threadIdx.x;
    int base = t * 29;                    // NN == 1024*29
    int loc[29];
    int s = 0;
    #pragma unroll
    for (int i = 0; i < 29; ++i) { loc[i] = s; s += cnt[base + i]; }
    part[t] = s;
    __syncthreads();
    for (int d = 1; d < 1024; d <<= 1) {
        int v = (t >= d) ? part[t - d] : 0;
        __syncthreads();
        part[t] += v;
        __syncthreads();
    }
    int pre = (t == 0) ? 0 : part[t - 1];
    #pragma unroll
    for (int i = 0; i < 29; ++i) {
        int v = pre + loc[i];
        rowStart[base + i] = v;
        cursor[base + i] = v;
    }
    if (t == 1023) rowStart[NN] = pre + s;
}

__global__ void k_scatter(const int* __restrict__ eidx, const int* __restrict__ flags,
                          int* __restrict__ cursor,
                          int* __restrict__ rS, int* __restrict__ cS) {
    int e = blockIdx.x * 256 + threadIdx.x;
    if (e >= NE) return;
    int is64 = flags[1];
    long ge = e, gc = (long)e + NE;
    int r = eidx[is64 ? 2*ge : ge];
    int c = eidx[is64 ? 2*gc : gc];
    int p = atomicAdd(&cursor[r], 1);
    rS[p] = r; cS[p] = c;
}

// ---------------------------------------------------------------------------
__global__ void k_hz(const float* __restrict__ z, const float* __restrict__ lw,
                     const float* __restrict__ lb, float* __restrict__ hz) {
    __shared__ float zs[LAT];
    int b = blockIdx.x;
    int c = threadIdx.x;
    if (c < LAT) zs[c] = z[b*LAT + c];
    __syncthreads();
    float acc = lb[c];
    #pragma unroll
    for (int k = 0; k < LAT; ++k) acc += zs[k] * lw[k*HID + c];
    hz[b*HID + c] = acc;
}

__global__ void k_init_h(const float* __restrict__ hz, const float* __restrict__ at,
                         const float* __restrict__ aw, const float* __restrict__ ab,
                         float* __restrict__ h) {
    __shared__ float ats[AF];
    int n = blockIdx.x;
    int c = threadIdx.x;
    int b = n / NA;
    if (c < AF) ats[c] = at[n*AF + c];
    __syncthreads();
    float acc = hz[b*HID + c] + ab[c];
    #pragma unroll
    for (int f = 0; f < AF; ++f) acc += ats[f] * aw[f*HID + c];
    h[(long)n*HID + c] = acc;
}

__global__ void k_init_pos(const float* __restrict__ ic, float* __restrict__ pos) {
    int i = blockIdx.x * blockDim.x + threadIdx.x;
    if (i >= NN*3) return;
    int n = i / 3, d = i - n*3;
    int a = n % NA;
    pos[i] = ic[a*3 + d];
}

__global__ void k_zero(float* __restrict__ agg, float* __restrict__ upd) {
    int i = blockIdx.x * blockDim.x + threadIdx.x;
    if (i < NN*HID) agg[i] = 0.f;
    if (i < NN*3)   upd[i] = 0.f;
}

// ---------------------------------------------------------------------------
// MFMA edge kernel on row-sorted edges; segmented agg reduction in LDS.
__global__ __launch_bounds__(256) void k_edge_mfma(
    const short* __restrict__ hb, const float* __restrict__ pos,
    const int* __restrict__ rS, const int* __restrict__ cS,
    const short* __restrict__ w1p, const float* __restrict__ w1last,
    const float* __restrict__ b1,
    const short* __restrict__ w2p, const float* __restrict__ b2,
    const short* __restrict__ c1p, const float* __restrict__ cb1,
    const float* __restrict__ cw2,
    float* __restrict__ agg, float* __restrict__ upd)
{
    __shared__ short ef[ET][264];       // xi|xj bf16; aliased by mmf (f32) later
    __shared__ short t1[ET][144];       // t1 bf16; later mm bf16
    __shared__ int   rIs[ET], cIs[ET];
    __shared__ float relS[ET][3];
    __shared__ float d2s[ET];
    __shared__ float sred[ET];
    float (*mmf)[132] = (float (*)[132])&ef[0][0];   // f32 messages for reduction

    const int tid = threadIdx.x;
    const long eb = (long)blockIdx.x * ET;

    if (tid < ET) {
        int r  = rS[eb + tid];
        int cn = cS[eb + tid];
        rIs[tid] = r; cIs[tid] = cn;
        float rx = pos[r*3+0] - pos[cn*3+0];
        float ry = pos[r*3+1] - pos[cn*3+1];
        float rz = pos[r*3+2] - pos[cn*3+2];
        relS[tid][0] = rx; relS[tid][1] = ry; relS[tid][2] = rz;
        float d2 = rx*rx + ry*ry + rz*rz;
        d2s[tid] = fminf(fmaxf(d2, 1e-6f), 1e6f);
        sred[tid] = 0.f;
    }
    __syncthreads();

    // gather xi/xj rows (bf16, 16B chunks)
    #pragma unroll
    for (int it = 0; it < 8; ++it) {
        int idx = it*256 + tid;
        int e = idx >> 5, c16 = idx & 31;
        int node = (c16 & 16) ? cIs[e] : rIs[e];
        int q = c16 & 15;
        int4 v = *(const int4*)(hb + (long)node*HID + q*8);
        *(int4*)&ef[e][c16*8] = v;
    }
    __syncthreads();

    const int l = tid & 63, w = tid >> 6;
    const int l16 = l & 15, quad = l >> 4;
    const int nt0 = 2*w, nt1 = 2*w + 1;
    const int c0 = nt0*16 + l16, c1c = nt1*16 + l16;
    const int half = tid >> 7, ch = tid & 127;

    // ---- stage 1: t1 = silu(ef @ w1 + b1) + f32 d2 term
    {
        f4 acc[4][2];
        #pragma unroll
        for (int mt = 0; mt < 4; ++mt) { acc[mt][0] = (f4)0.f; acc[mt][1] = (f4)0.f; }
        #pragma unroll
        for (int kc = 0; kc < 8; ++kc) {
            s8 b0  = *(const s8*)(w1p + (((size_t)nt0*8 + kc)*64 + l)*8);
            s8 b1f = *(const s8*)(w1p + (((size_t)nt1*8 + kc)*64 + l)*8);
            #pragma unroll
            for (int mt = 0; mt < 4; ++mt) {
                s8 a = *(const s8*)&ef[mt*16 + l16][kc*32 + quad*8];
                acc[mt][0] = __builtin_amdgcn_mfma_f32_16x16x32_bf16(a, b0,  acc[mt][0], 0, 0, 0);
                acc[mt][1] = __builtin_amdgcn_mfma_f32_16x16x32_bf16(a, b1f, acc[mt][1], 0, 0, 0);
            }
        }
        float bia0 = b1[c0], bia1 = b1[c1c];
        float wl0 = w1last[c0], wl1 = w1last[c1c];
        #pragma unroll
        for (int mt = 0; mt < 4; ++mt) {
            #pragma unroll
            for (int i = 0; i < 4; ++i) {
                int row = mt*16 + quad*4 + i;
                float d2 = d2s[row];
                t1[row][c0]  = f2b(siluf(acc[mt][0][i] + bia0 + d2*wl0));
                t1[row][c1c] = f2b(siluf(acc[mt][1][i] + bia1 + d2*wl1));
            }
        }
    }
    __syncthreads();

    // ---- stage 2: m = silu(t1 @ w2 + b2) -> mm bf16 (t1 region) + mmf f32 (ef region)
    {
        f4 acc[4][2];
        #pragma unroll
        for (int mt = 0; mt < 4; ++mt) { acc[mt][0] = (f4)0.f; acc[mt][1] = (f4)0.f; }
        #pragma unroll
        for (int kc = 0; kc < 4; ++kc) {
            s8 b0  = *(const s8*)(w2p + (((size_t)nt0*4 + kc)*64 + l)*8);
            s8 b1f = *(const s8*)(w2p + (((size_t)nt1*4 + kc)*64 + l)*8);
            #pragma unroll
            for (int mt = 0; mt < 4; ++mt) {
                s8 a = *(const s8*)&t1[mt*16 + l16][kc*32 + quad*8];
                acc[mt][0] = __builtin_amdgcn_mfma_f32_16x16x32_bf16(a, b0,  acc[mt][0], 0, 0, 0);
                acc[mt][1] = __builtin_amdgcn_mfma_f32_16x16x32_bf16(a, b1f, acc[mt][1], 0, 0, 0);
            }
        }
        float bia0 = b2[c0], bia1 = b2[c1c];
        __syncthreads();     // all t1/ef reads done before overwrite
        #pragma unroll
        for (int mt = 0; mt < 4; ++mt) {
            #pragma unroll
            for (int i = 0; i < 4; ++i) {
                int row = mt*16 + quad*4 + i;
                float m0 = siluf(acc[mt][0][i] + bia0);
                float m1 = siluf(acc[mt][1][i] + bia1);
                t1[row][c0]  = f2b(m0);
                t1[row][c1c] = f2b(m1);
                mmf[row][c0]  = m0;
                mmf[row][c1c] = m1;
            }
        }
    }
    __syncthreads();

    // ---- stage 3: c1 = silu(mm @ cw1 + cb1); dot with cw2 -> sred
    {
        f4 acc[4][2];
        #pragma unroll
        for (int mt = 0; mt < 4; ++mt) { acc[mt][0] = (f4)0.f; acc[mt][1] = (f4)0.f; }
        #pragma unroll
        for (int kc = 0; kc < 4; ++kc) {
            s8 b0  = *(const s8*)(c1p + (((size_t)nt0*4 + kc)*64 + l)*8);
            s8 b1f = *(const s8*)(c1p + (((size_t)nt1*4 + kc)*64 + l)*8);
            #pragma unroll
            for (int mt = 0; mt < 4; ++mt) {
                s8 a = *(const s8*)&t1[mt*16 + l16][kc*32 + quad*8];
                acc[mt][0] = __builtin_amdgcn_mfma_f32_16x16x32_bf16(a, b0,  acc[mt][0], 0, 0, 0);
                acc[mt][1] = __builtin_amdgcn_mfma_f32_16x16x32_bf16(a, b1f, acc[mt][1], 0, 0, 0);
            }
        }
        float bia0 = cb1[c0], bia1 = cb1[c1c];
        float cw0 = cw2[c0], cw1v = cw2[c1c];
        #pragma unroll
        for (int mt = 0; mt < 4; ++mt) {
            #pragma unroll
            for (int i = 0; i < 4; ++i) {
                float p = siluf(acc[mt][0][i] + bia0) * cw0
                        + siluf(acc[mt][1][i] + bia1) * cw1v;
                p += __shfl_xor(p, 1);
                p += __shfl_xor(p, 2);
                p += __shfl_xor(p, 4);
                p += __shfl_xor(p, 8);
                if (l16 == 0) {
                    int row = mt*16 + quad*4 + i;
                    atomicAdd(&sred[row], p);
                }
            }
        }
    }

    // ---- segmented agg reduction over sorted rows (f32, few atomics/block)
    {
        int e0 = half * 32;
        int cur = rIs[e0];
        float a = 0.f;
        #pragma unroll
        for (int e = e0; e < e0 + 32; ++e) {
            int r = rIs[e];
            if (r != cur) {
                atomicAdd(&agg[(long)cur*HID + ch], a);
                a = 0.f; cur = r;
            }
            a += mmf[e][ch];
        }
        atomicAdd(&agg[(long)cur*HID + ch], a);
    }
    __syncthreads();

    if (tid < ET) {
        float cwv = fminf(fmaxf(sred[tid], -1.f), 1.f);
        int r = rIs[tid];
        atomicAdd(&upd[r*3+0], cwv*relS[tid][0]);
        atomicAdd(&upd[r*3+1], cwv*relS[tid][1]);
        atomicAdd(&upd[r*3+2], cwv*relS[tid][2]);
    }
}

// ---------------------------------------------------------------------------
// MFMA node kernel: 64 nodes/block; x=[h|agg] bf16; LN in f32; writes h + hb.
__global__ __launch_bounds__(256) void k_node_mfma(
    float* __restrict__ h, short* __restrict__ hb, const float* __restrict__ agg,
    const short* __restrict__ w1p, const float* __restrict__ b1n,
    const short* __restrict__ w2p, const float* __restrict__ b2n,
    const float* __restrict__ lg, const float* __restrict__ lb,
    float* __restrict__ pos, const float* __restrict__ upd,
    const int* __restrict__ rowStart)
{
    __shared__ short x[64][264];
    __shared__ short t1[64][144];
    __shared__ float mus[64], rstds[64];
    float (*hn)[132] = (float (*)[132])&x[0][0];

    const int tid = threadIdx.x;
    const int n0 = blockIdx.x * 64;

    #pragma unroll
    for (int it = 0; it < 4; ++it) {
        int idx = it*256 + tid;             // 1024 chunks of 16B (h bf16)
        int e = idx >> 4, q = idx & 15;
        *(int4*)&x[e][q*8] = *(const int4*)(hb + (long)(n0+e)*HID + q*8);
    }
    #pragma unroll
    for (int it = 0; it < 8; ++it) {
        int idx = it*256 + tid;             // 2048 chunks of 4 floats (agg)
        int e = idx >> 5, q = idx & 31;
        float4 v = *(const float4*)(agg + (long)(n0+e)*HID + q*4);
        short4 sv;
        sv.x = f2b(v.x); sv.y = f2b(v.y); sv.z = f2b(v.z); sv.w = f2b(v.w);
        *(short4*)&x[e][128 + q*4] = sv;
    }
    __syncthreads();

    const int l = tid & 63, w = tid >> 6;
    const int l16 = l & 15, quad = l >> 4;
    const int nt0 = 2*w, nt1 = 2*w + 1;
    const int c0 = nt0*16 + l16, c1c = nt1*16 + l16;

    // GEMM1 K=256: t1 = silu(x @ w1 + b1)
    {
        f4 acc[4][2];
        #pragma unroll
        for (int mt = 0; mt < 4; ++mt) { acc[mt][0] = (f4)0.f; acc[mt][1] = (f4)0.f; }
        #pragma unroll
        for (int kc = 0; kc < 8; ++kc) {
            s8 b0  = *(const s8*)(w1p + (((size_t)nt0*8 + kc)*64 + l)*8);
            s8 b1f = *(const s8*)(w1p + (((size_t)nt1*8 + kc)*64 + l)*8);
            #pragma unroll
            for (int mt = 0; mt < 4; ++mt) {
                s8 a = *(const s8*)&x[mt*16 + l16][kc*32 + quad*8];
                acc[mt][0] = __builtin_amdgcn_mfma_f32_16x16x32_bf16(a, b0,  acc[mt][0], 0, 0, 0);
                acc[mt][1] = __builtin_amdgcn_mfma_f32_16x16x32_bf16(a, b1f, acc[mt][1], 0, 0, 0);
            }
        }
        float bia0 = b1n[c0], bia1 = b1n[c1c];
        #pragma unroll
        for (int mt = 0; mt < 4; ++mt) {
            #pragma unroll
            for (int i = 0; i < 4; ++i) {
                int row = mt*16 + quad*4 + i;
                t1[row][c0]  = f2b(siluf(acc[mt][0][i] + bia0));
                t1[row][c1c] = f2b(siluf(acc[mt][1][i] + bia1));
            }
        }
    }
    __syncthreads();

    // GEMM2 K=128: hn = t1 @ w2 + b2 (no activation), f32 into x-alias
    {
        f4 acc[4][2];
        #pragma unroll
        for (int mt = 0; mt < 4; ++mt) { acc[mt][0] = (f4)0.f; acc[mt][1] = (f4)0.f; }
        #pragma unroll
        for (int kc = 0; kc < 4; ++kc) {
            s8 b0  = *(const s8*)(w2p + (((size_t)nt0*4 + kc)*64 + l)*8);
            s8 b1f = *(const s8*)(w2p + (((size_t)nt1*4 + kc)*64 + l)*8);
            #pragma unroll
            for (int mt = 0; mt < 4; ++mt) {
                s8 a = *(const s8*)&t1[mt*16 + l16][kc*32 + quad*8];
                acc[mt][0] = __builtin_amdgcn_mfma_f32_16x16x32_bf16(a, b0,  acc[mt][0], 0, 0, 0);
                acc[mt][1] = __builtin_amdgcn_mfma_f32_16x16x32_bf16(a, b1f, acc[mt][1], 0, 0, 0);
            }
        }
        float bia0 = b2n[c0], bia1 = b2n[c1c];
        __syncthreads();     // x reads fully done before hn overwrite
        #pragma unroll
        for (int mt = 0; mt < 4; ++mt) {
            #pragma unroll
            for (int i = 0; i < 4; ++i) {
                int row = mt*16 + quad*4 + i;
                hn[row][c0]  = acc[mt][0][i] + bia0;
                hn[row][c1c] = acc[mt][1][i] + bia1;
            }
        }
    }
    __syncthreads();

    // LayerNorm stats: 4 lanes per row, stride-4 columns
    {
        int r = tid >> 2, part = tid & 3;
        float s = 0.f, q = 0.f;
        #pragma unroll
        for (int j = 0; j < 32; ++j) {
            float v = hn[r][part + 4*j];
            s += v; q += v*v;
        }
        s += __shfl_xor(s, 1); q += __shfl_xor(q, 1);
        s += __shfl_xor(s, 2); q += __shfl_xor(q, 2);
        if (part == 0) {
            float mu = s * (1.0f/HID);
            float var = q * (1.0f/HID) - mu*mu;
            mus[r] = mu;
            rstds[r] = rsqrtf(var + 1e-5f);
        }
    }
    __syncthreads();

    // normalized output: h (f32) + hb (bf16), coalesced
    #pragma unroll
    for (int it = 0; it < 32; ++it) {
        int idx = it*256 + tid;
        int r = idx >> 7, c = idx & 127;
        float v = (hn[r][c] - mus[r]) * rstds[r] * lg[c] + lb[c];
        long o = (long)(n0 + r)*HID + c;
        h[o] = v;
        hb[o] = f2b(v);
    }
    if (tid < 192) {
        int i = tid / 3, d = tid - i*3;
        int n = n0 + i;
        float dg = (float)(rowStart[n+1] - rowStart[n]);
        pos[n*3+d] += upd[n*3+d] / (dg + 1e-6f);
    }
}

// ---------------------------------------------------------------------------
__global__ void k_head(const float* __restrict__ h, const float* __restrict__ pos,
                       const float* __restrict__ w1, const float* __restrict__ b1,
                       const float* __restrict__ w2, const float* __restrict__ b2,
                       void* __restrict__ out, const int* __restrict__ flags)
{
    __shared__ float hs[4][HID];
    __shared__ float t[4][64];
    const int tid = threadIdx.x;
    const int n0 = blockIdx.x * 4;
    for (int i = tid; i < 4*HID; i += 256) hs[i >> 7][i & 127] = h[(long)n0*HID + i];
    __syncthreads();
    const int s = tid >> 6, c = tid & 63;
    float acc = b1[c];
    for (int k4 = 0; k4 < 32; ++k4) {
        int k = k4*4;
        float wa = w1[(k+0)*64 + c];
        float wb = w1[(k+1)*64 + c];
        float wc = w1[(k+2)*64 + c];
        float wd = w1[(k+3)*64 + c];
        float4 v = *(const float4*)&hs[s][k];
        acc += v.x*wa + v.y*wb + v.z*wc + v.w*wd;
    }
    t[s][c] = siluf(acc);
    __syncthreads();
    if (c < 3) {
        float a2 = b2[c];
        #pragma unroll
        for (int k = 0; k < 64; ++k) a2 += t[s][k] * w2[k*3 + c];
        int n = n0 + s;
        float v = pos[n*3+c] + a2;
        if (flags[0]) ((__hip_bfloat16*)out)[n*3+c] = __float2bfloat16(v);
        else          ((float*)out)[n*3+c] = v;
    }
}

// ---------------------------------------------------------------------------
extern "C" void kernel_launch(void* const* d_in, const int* in_sizes, int n_in,
                              void* d_out, int out_size, void* d_ws, size_t ws_size,
                              hipStream_t stream)
{
    (void)in_sizes; (void)n_in; (void)out_size; (void)ws_size;

    int* flags = (int*)d_ws;
    float* base = (float*)d_ws;
    size_t off = 64;
    auto alloc = [&](size_t n) { float* p = base + off; off += (n + 63) & ~63ull; return p; };

    static const int aidx[24] = {0,1,3,4,5,6,7,8,9,10,11,12,13,14,15,16,17,18,19,20,21,22,23,24};
    static const int alen[24] = {
        BB*LAT, NN*AF, NA*3, LAT*HID, HID, AF*HID, HID,
        NL*257*HID, NL*HID, NL*HID*HID, NL*HID,
        NL*256*HID, NL*HID, NL*HID*HID, NL*HID,
        NL*HID*HID, NL*HID, NL*HID, NL*HID, NL*HID,
        HID*64, 64, 64*3, 3
    };
    CvtDesc cd;
    float* fp[24];
    for (int a = 0; a < 24; ++a) {
        fp[a] = alloc((size_t)alen[a]);
        cd.src[a] = d_in[aidx[a]];
        cd.dst[a] = fp[a];
        cd.len[a] = alen[a];
    }
    float* h   = alloc((size_t)NN*HID);
    float* agg = alloc((size_t)NN*HID);
    float* hz  = alloc((size_t)BB*HID);
    float* pos = alloc((size_t)NN*3);
    float* upd = alloc((size_t)NN*3);
    short* hb  = (short*)alloc((size_t)NN*HID/2);
    short* w1p = (short*)alloc((size_t)NL*32768/2);
    short* w2p = (short*)alloc((size_t)NL*16384/2);
    short* c1p = (short*)alloc((size_t)NL*16384/2);
    short* nw1p = (short*)alloc((size_t)NL*32768/2);
    short* nw2p = (short*)alloc((size_t)NL*16384/2);
    int* cnt      = (int*)alloc((size_t)NN);
    int* rowStart = (int*)alloc((size_t)NN + 1);
    int* cursor   = (int*)alloc((size_t)NN);
    int* rS       = (int*)alloc((size_t)NE);
    int* cS       = (int*)alloc((size_t)NE);
    const int* eidx = (const int*)d_in[2];

    k_detect<<<1, 256, 0, stream>>>((const unsigned short*)d_in[0],
                                    (const unsigned int*)d_in[2], flags);
    k_convert<<<dim3((NN*AF + 255)/256, 24), 256, 0, stream>>>(cd, flags);

    for (int l = 0; l < NL; ++l) {
        k_pack<<<128, 256, 0, stream>>>(fp[7]  + (size_t)l*257*HID, w1p  + (size_t)l*32768, 256);
        k_pack<<<64,  256, 0, stream>>>(fp[9]  + (size_t)l*HID*HID, w2p  + (size_t)l*16384, 128);
        k_pack<<<64,  256, 0, stream>>>(fp[15] + (size_t)l*HID*HID, c1p  + (size_t)l*16384, 128);
        k_pack<<<128, 256, 0, stream>>>(fp[11] + (size_t)l*256*HID, nw1p + (size_t)l*32768, 256);
        k_pack<<<64,  256, 0, stream>>>(fp[13] + (size_t)l*HID*HID, nw2p + (size_t)l*16384, 128);
    }

    // counting sort edges by row
    k_zero_cnt<<<(NN + 255)/256, 256, 0, stream>>>(cnt);
    k_hist<<<(NE + 255)/256, 256, 0, stream>>>(eidx, flags, cnt);
    k_scan<<<1, 1024, 0, stream>>>(cnt, rowStart, cursor);
    k_scatter<<<(NE + 255)/256, 256, 0, stream>>>(eidx, flags, cursor, rS, cS);

    k_hz<<<BB, HID, 0, stream>>>(fp[0], fp[3], fp[4], hz);
    k_init_h<<<NN, HID, 0, stream>>>(hz, fp[1], fp[5], fp[6], h);
    k_init_pos<<<(NN*3 + 255)/256, 256, 0, stream>>>(fp[2], pos);
    k_h2b<<<(NN*HID + 255)/256, 256, 0, stream>>>(h, hb);

    for (int l = 0; l < NL; ++l) {
        k_zero<<<(NN*HID + 255)/256, 256, 0, stream>>>(agg, upd);
        k_edge_mfma<<<NE/ET, 256, 0, stream>>>(hb, pos, rS, cS,
            w1p + (size_t)l*32768,
            fp[7] + (size_t)l*257*HID + 256*HID,
            fp[8] + (size_t)l*HID,
            w2p + (size_t)l*16384, fp[10] + (size_t)l*HID,
            c1p + (size_t)l*16384, fp[16] + (size_t)l*HID,
            fp[17] + (size_t)l*HID,
            agg, upd);
        k_node_mfma<<<NN/64, 256, 0, stream>>>(h, hb, agg,
            nw1p + (size_t)l*32768, fp[12] + (size_t)l*HID,
            nw2p + (size_t)l*16384, fp[14] + (size_t)l*HID,
            fp[18] + (size_t)l*HID, fp[19] + (size_t)l*HID,
            pos, upd, rowStart);
    }
    k_head<<<NN/4, 256, 0, stream>>>(h, pos, fp[20], fp[21], fp[22], fp[23],
                                     d_out, flags);
}

// Round 4
// 905.201 us; speedup vs baseline: 3.7495x; 1.0771x over previous
//
#include <hip/hip_runtime.h>
#include <hip/hip_bf16.h>

#define BB 512
#define NA 58
#define LAT 64
#define HID 128
#define AF 10
#define NL 2
#define NN (BB*NA)      // 29696
#define NE (NN*16)      // 475136
#define ET 64           // edges per MFMA tile
#define NTILE (NE/ET)   // 7424
#define PBLK 512        // persistent blocks (2 per CU)

typedef __attribute__((ext_vector_type(8))) short s8;
typedef __attribute__((ext_vector_type(4))) float f4;

struct CvtDesc {
    const void* src[24];
    float*      dst[24];
    int         len[24];
};

__device__ __forceinline__ float siluf(float x) {
    return x / (1.0f + __expf(-x));
}

__device__ __forceinline__ short f2b(float x) {
    __hip_bfloat16 b = __float2bfloat16(x);
    return *(short*)&b;
}

// ---------------------------------------------------------------------------
__global__ void k_detect(const unsigned short* __restrict__ z16,
                         const unsigned int* __restrict__ e32,
                         int* __restrict__ flags) {
    __shared__ int sbf, si64;
    if (threadIdx.x == 0) { sbf = 0; si64 = 0; }
    __syncthreads();
    int c1 = 0, c2 = 0;
    for (int i = threadIdx.x; i < 1024; i += 256) {
        unsigned short v = z16[2*i];
        int e = (v >> 7) & 0xFF;
        if (e >= 100 && e <= 140) c1++;
        if (e32[2*i + 1] == 0u) c2++;
    }
    atomicAdd(&sbf, c1);
    atomicAdd(&si64, c2);
    __syncthreads();
    if (threadIdx.x == 0) {
        flags[0] = (sbf  > 600) ? 1 : 0;
        flags[1] = (si64 > 600) ? 1 : 0;
    }
}

__global__ void k_convert(CvtDesc d, const int* __restrict__ flags) {
    int a = blockIdx.y;
    int i = blockIdx.x * blockDim.x + threadIdx.x;
    int n = d.len[a];
    if (i >= n) return;
    if (flags[0]) {
        d.dst[a][i] = __bfloat162float(((const __hip_bfloat16*)d.src[a])[i]);
    } else {
        d.dst[a][i] = ((const float*)d.src[a])[i];
    }
}

// Pack f32 weight [K][128] into bf16 B-fragment order
__global__ void k_pack(const float* __restrict__ w, short* __restrict__ o, int K) {
    int idx = blockIdx.x * 256 + threadIdx.x;
    int total = 128 * K;
    if (idx >= total) return;
    int j  = idx & 7;
    int l  = (idx >> 3) & 63;
    int rest = idx >> 9;
    int KC = K >> 5;
    int kc = rest % KC;
    int nt = rest / KC;
    int n = nt*16 + (l & 15);
    int k = kc*32 + (l >> 4)*8 + j;
    o[idx] = f2b(w[k*128 + n]);
}

__global__ void k_h2b(const float* __restrict__ h, short* __restrict__ hb) {
    int i = blockIdx.x * 256 + threadIdx.x;
    if (i < NN*HID) hb[i] = f2b(h[i]);
}

// ---------------------------------------------------------------------------
// counting sort of edges by row
__global__ void k_zero_cnt(int* __restrict__ cnt) {
    int i = blockIdx.x * 256 + threadIdx.x;
    if (i < NN) cnt[i] = 0;
}

__global__ void k_hist(const int* __restrict__ eidx, const int* __restrict__ flags,
                       int* __restrict__ cnt) {
    int e = blockIdx.x * 256 + threadIdx.x;
    if (e >= NE) return;
    int is64 = flags[1];
    int r = eidx[is64 ? 2*(long)e : (long)e];
    atomicAdd(&cnt[r], 1);
}

__global__ __launch_bounds__(1024) void k_scan(const int* __restrict__ cnt,
                                               int* __restrict__ rowStart,
                                               int* __restrict__ cursor) {
    __shared__ int part[1024];
    int t = threadIdx.x;
    int base = t * 29;                    // NN == 1024*29
    int loc[29];
    int s = 0;
    #pragma unroll
    for (int i = 0; i < 29; ++i) { loc[i] = s; s += cnt[base + i]; }
    part[t] = s;
    __syncthreads();
    for (int d = 1; d < 1024; d <<= 1) {
        int v = (t >= d) ? part[t - d] : 0;
        __syncthreads();
        part[t] += v;
        __syncthreads();
    }
    int pre = (t == 0) ? 0 : part[t - 1];
    #pragma unroll
    for (int i = 0; i < 29; ++i) {
        int v = pre + loc[i];
        rowStart[base + i] = v;
        cursor[base + i] = v;
    }
    if (t == 1023) rowStart[NN] = pre + s;
}

__global__ void k_scatter(const int* __restrict__ eidx, const int* __restrict__ flags,
                          int* __restrict__ cursor,
                          int* __restrict__ rS, int* __restrict__ cS) {
    int e = blockIdx.x * 256 + threadIdx.x;
    if (e >= NE) return;
    int is64 = flags[1];
    long ge = e, gc = (long)e + NE;
    int r = eidx[is64 ? 2*ge : ge];
    int c = eidx[is64 ? 2*gc : gc];
    int p = atomicAdd(&cursor[r], 1);
    rS[p] = r; cS[p] = c;
}

// ---------------------------------------------------------------------------
__global__ void k_hz(const float* __restrict__ z, const float* __restrict__ lw,
                     const float* __restrict__ lb, float* __restrict__ hz) {
    __shared__ float zs[LAT];
    int b = blockIdx.x;
    int c = threadIdx.x;
    if (c < LAT) zs[c] = z[b*LAT + c];
    __syncthreads();
    float acc = lb[c];
    #pragma unroll
    for (int k = 0; k < LAT; ++k) acc += zs[k] * lw[k*HID + c];
    hz[b*HID + c] = acc;
}

__global__ void k_init_h(const float* __restrict__ hz, const float* __restrict__ at,
                         const float* __restrict__ aw, const float* __restrict__ ab,
                         float* __restrict__ h) {
    __shared__ float ats[AF];
    int n = blockIdx.x;
    int c = threadIdx.x;
    int b = n / NA;
    if (c < AF) ats[c] = at[n*AF + c];
    __syncthreads();
    float acc = hz[b*HID + c] + ab[c];
    #pragma unroll
    for (int f = 0; f < AF; ++f) acc += ats[f] * aw[f*HID + c];
    h[(long)n*HID + c] = acc;
}

__global__ void k_init_pos(const float* __restrict__ ic, float* __restrict__ pos) {
    int i = blockIdx.x * blockDim.x + threadIdx.x;
    if (i >= NN*3) return;
    int n = i / 3, d = i - n*3;
    int a = n % NA;
    pos[i] = ic[a*3 + d];
}

__global__ void k_zero(float* __restrict__ agg, float* __restrict__ upd) {
    int i = blockIdx.x * blockDim.x + threadIdx.x;
    if (i < NN*HID) agg[i] = 0.f;
    if (i < NN*3)   upd[i] = 0.f;
}

// ---------------------------------------------------------------------------
// Persistent MFMA edge kernel: 512 blocks, each strides over ~14.5 tiles.
// Weights resident in VGPRs; next tile's gather prefetched into registers.
#define PREFETCH(T) do {                                                      \
    long eb = (long)(T) * ET;                                                 \
    if (tid < ET) {                                                           \
        pr_r = rS[eb + tid];                                                  \
        int pc = cS[eb + tid];                                                \
        float rx = pos[pr_r*3+0] - pos[pc*3+0];                               \
        float ry = pos[pr_r*3+1] - pos[pc*3+1];                               \
        float rz = pos[pr_r*3+2] - pos[pc*3+2];                               \
        pr_rel0 = rx; pr_rel1 = ry; pr_rel2 = rz;                             \
        pr_d2 = fminf(fmaxf(rx*rx + ry*ry + rz*rz, 1e-6f), 1e6f);             \
    }                                                                         \
    _Pragma("unroll")                                                         \
    for (int it = 0; it < 8; ++it) {                                          \
        int idx = it*256 + tid;                                               \
        int e = idx >> 5, c16 = idx & 31;                                     \
        int node = (c16 & 16) ? cS[eb + e] : rS[eb + e];                      \
        g[it] = *(const int4*)(hb + (long)node*HID + (c16 & 15)*8);           \
    }                                                                         \
} while (0)

__global__ __launch_bounds__(256, 2) void k_edge_mfma(
    const short* __restrict__ hb, const float* __restrict__ pos,
    const int* __restrict__ rS, const int* __restrict__ cS,
    const short* __restrict__ w1p, const float* __restrict__ w1last,
    const float* __restrict__ b1,
    const short* __restrict__ w2p, const float* __restrict__ b2,
    const short* __restrict__ c1p, const float* __restrict__ cb1,
    const float* __restrict__ cw2,
    float* __restrict__ agg, float* __restrict__ upd)
{
    __shared__ short ef[ET][264];       // xi|xj bf16; aliased by mmf (f32)
    __shared__ short t1[ET][144];       // t1 bf16; then mm bf16
    __shared__ int   rIs[ET];
    __shared__ float relS[ET][3];
    __shared__ float d2s[ET];
    __shared__ float sred[ET];
    float (*mmf)[132] = (float (*)[132])&ef[0][0];

    const int tid = threadIdx.x;
    const int l = tid & 63, w = tid >> 6;
    const int l16 = l & 15, quad = l >> 4;
    const int nt0 = 2*w, nt1 = 2*w + 1;
    const int c0 = nt0*16 + l16, c1c = nt1*16 + l16;
    const int half = tid >> 7, ch = tid & 127;

    // ---- load weights once per wave into registers
    s8 w1f[16], w2f[8], c1f[8];
    #pragma unroll
    for (int kc = 0; kc < 8; ++kc) {
        w1f[kc]     = *(const s8*)(w1p + (((size_t)nt0*8 + kc)*64 + l)*8);
        w1f[8 + kc] = *(const s8*)(w1p + (((size_t)nt1*8 + kc)*64 + l)*8);
    }
    #pragma unroll
    for (int kc = 0; kc < 4; ++kc) {
        w2f[kc]     = *(const s8*)(w2p + (((size_t)nt0*4 + kc)*64 + l)*8);
        w2f[4 + kc] = *(const s8*)(w2p + (((size_t)nt1*4 + kc)*64 + l)*8);
        c1f[kc]     = *(const s8*)(c1p + (((size_t)nt0*4 + kc)*64 + l)*8);
        c1f[4 + kc] = *(const s8*)(c1p + (((size_t)nt1*4 + kc)*64 + l)*8);
    }
    const float bia1_0 = b1[c0],  bia1_1 = b1[c1c];
    const float wl0    = w1last[c0], wl1 = w1last[c1c];
    const float bia2_0 = b2[c0],  bia2_1 = b2[c1c];
    const float biac_0 = cb1[c0], biac_1 = cb1[c1c];
    const float cw0    = cw2[c0], cw1v   = cw2[c1c];

    // prefetch registers
    int4 g[8];
    int pr_r = 0;
    float pr_rel0 = 0.f, pr_rel1 = 0.f, pr_rel2 = 0.f, pr_d2 = 0.f;

    int t = blockIdx.x;
    PREFETCH(t);

    while (t < NTILE) {
        __syncthreads();                        // prior tile's LDS reads done
        // ---- commit prefetched tile to LDS
        if (tid < ET) {
            rIs[tid] = pr_r;
            relS[tid][0] = pr_rel0; relS[tid][1] = pr_rel1; relS[tid][2] = pr_rel2;
            d2s[tid] = pr_d2;
            sred[tid] = 0.f;
        }
        #pragma unroll
        for (int it = 0; it < 8; ++it) {
            int idx = it*256 + tid;
            int e = idx >> 5, c16 = idx & 31;
            *(int4*)&ef[e][c16*8] = g[it];
        }
        __syncthreads();

        int tn = t + PBLK;
        if (tn < NTILE) PREFETCH(tn);           // overlaps all 3 MFMA stages

        // ---- stage 1: t1 = silu(ef @ w1 + b1) + f32 d2 term
        {
            f4 acc[4][2];
            #pragma unroll
            for (int mt = 0; mt < 4; ++mt) { acc[mt][0] = (f4)0.f; acc[mt][1] = (f4)0.f; }
            #pragma unroll
            for (int kc = 0; kc < 8; ++kc) {
                #pragma unroll
                for (int mt = 0; mt < 4; ++mt) {
                    s8 a = *(const s8*)&ef[mt*16 + l16][kc*32 + quad*8];
                    acc[mt][0] = __builtin_amdgcn_mfma_f32_16x16x32_bf16(a, w1f[kc],     acc[mt][0], 0, 0, 0);
                    acc[mt][1] = __builtin_amdgcn_mfma_f32_16x16x32_bf16(a, w1f[8 + kc], acc[mt][1], 0, 0, 0);
                }
            }
            #pragma unroll
            for (int mt = 0; mt < 4; ++mt) {
                #pragma unroll
                for (int i = 0; i < 4; ++i) {
                    int row = mt*16 + quad*4 + i;
                    float d2 = d2s[row];
                    t1[row][c0]  = f2b(siluf(acc[mt][0][i] + bia1_0 + d2*wl0));
                    t1[row][c1c] = f2b(siluf(acc[mt][1][i] + bia1_1 + d2*wl1));
                }
            }
        }
        __syncthreads();

        // ---- stage 2: m = silu(t1 @ w2 + b2) -> mm bf16 (t1) + mmf f32 (ef)
        {
            f4 acc[4][2];
            #pragma unroll
            for (int mt = 0; mt < 4; ++mt) { acc[mt][0] = (f4)0.f; acc[mt][1] = (f4)0.f; }
            #pragma unroll
            for (int kc = 0; kc < 4; ++kc) {
                #pragma unroll
                for (int mt = 0; mt < 4; ++mt) {
                    s8 a = *(const s8*)&t1[mt*16 + l16][kc*32 + quad*8];
                    acc[mt][0] = __builtin_amdgcn_mfma_f32_16x16x32_bf16(a, w2f[kc],     acc[mt][0], 0, 0, 0);
                    acc[mt][1] = __builtin_amdgcn_mfma_f32_16x16x32_bf16(a, w2f[4 + kc], acc[mt][1], 0, 0, 0);
                }
            }
            __syncthreads();     // all t1/ef reads done before overwrite
            #pragma unroll
            for (int mt = 0; mt < 4; ++mt) {
                #pragma unroll
                for (int i = 0; i < 4; ++i) {
                    int row = mt*16 + quad*4 + i;
                    float m0 = siluf(acc[mt][0][i] + bia2_0);
                    float m1 = siluf(acc[mt][1][i] + bia2_1);
                    t1[row][c0]  = f2b(m0);
                    t1[row][c1c] = f2b(m1);
                    mmf[row][c0]  = m0;
                    mmf[row][c1c] = m1;
                }
            }
        }
        __syncthreads();

        // ---- stage 3: c1 = silu(mm @ cw1 + cb1); dot with cw2 -> sred
        {
            f4 acc[4][2];
            #pragma unroll
            for (int mt = 0; mt < 4; ++mt) { acc[mt][0] = (f4)0.f; acc[mt][1] = (f4)0.f; }
            #pragma unroll
            for (int kc = 0; kc < 4; ++kc) {
                #pragma unroll
                for (int mt = 0; mt < 4; ++mt) {
                    s8 a = *(const s8*)&t1[mt*16 + l16][kc*32 + quad*8];
                    acc[mt][0] = __builtin_amdgcn_mfma_f32_16x16x32_bf16(a, c1f[kc],     acc[mt][0], 0, 0, 0);
                    acc[mt][1] = __builtin_amdgcn_mfma_f32_16x16x32_bf16(a, c1f[4 + kc], acc[mt][1], 0, 0, 0);
                }
            }
            #pragma unroll
            for (int mt = 0; mt < 4; ++mt) {
                #pragma unroll
                for (int i = 0; i < 4; ++i) {
                    float p = siluf(acc[mt][0][i] + biac_0) * cw0
                            + siluf(acc[mt][1][i] + biac_1) * cw1v;
                    p += __shfl_xor(p, 1);
                    p += __shfl_xor(p, 2);
                    p += __shfl_xor(p, 4);
                    p += __shfl_xor(p, 8);
                    if (l16 == 0) {
                        int row = mt*16 + quad*4 + i;
                        atomicAdd(&sred[row], p);
                    }
                }
            }
        }

        // ---- segmented agg reduction over sorted rows
        {
            int e0 = half * 32;
            int cur = rIs[e0];
            float a = 0.f;
            #pragma unroll
            for (int e = e0; e < e0 + 32; ++e) {
                int r = rIs[e];
                if (r != cur) {
                    atomicAdd(&agg[(long)cur*HID + ch], a);
                    a = 0.f; cur = r;
                }
                a += mmf[e][ch];
            }
            atomicAdd(&agg[(long)cur*HID + ch], a);
        }
        __syncthreads();

        if (tid < ET) {
            float cwv = fminf(fmaxf(sred[tid], -1.f), 1.f);
            int r = rIs[tid];
            atomicAdd(&upd[r*3+0], cwv*relS[tid][0]);
            atomicAdd(&upd[r*3+1], cwv*relS[tid][1]);
            atomicAdd(&upd[r*3+2], cwv*relS[tid][2]);
        }
        t = tn;
    }
}

// ---------------------------------------------------------------------------
// MFMA node kernel: 64 nodes/block; x=[h|agg] bf16; LN in f32; writes h + hb.
__global__ __launch_bounds__(256) void k_node_mfma(
    float* __restrict__ h, short* __restrict__ hb, const float* __restrict__ agg,
    const short* __restrict__ w1p, const float* __restrict__ b1n,
    const short* __restrict__ w2p, const float* __restrict__ b2n,
    const float* __restrict__ lg, const float* __restrict__ lb,
    float* __restrict__ pos, const float* __restrict__ upd,
    const int* __restrict__ rowStart)
{
    __shared__ short x[64][264];
    __shared__ short t1[64][144];
    __shared__ float mus[64], rstds[64];
    float (*hn)[132] = (float (*)[132])&x[0][0];

    const int tid = threadIdx.x;
    const int n0 = blockIdx.x * 64;

    #pragma unroll
    for (int it = 0; it < 4; ++it) {
        int idx = it*256 + tid;
        int e = idx >> 4, q = idx & 15;
        *(int4*)&x[e][q*8] = *(const int4*)(hb + (long)(n0+e)*HID + q*8);
    }
    #pragma unroll
    for (int it = 0; it < 8; ++it) {
        int idx = it*256 + tid;
        int e = idx >> 5, q = idx & 31;
        float4 v = *(const float4*)(agg + (long)(n0+e)*HID + q*4);
        short4 sv;
        sv.x = f2b(v.x); sv.y = f2b(v.y); sv.z = f2b(v.z); sv.w = f2b(v.w);
        *(short4*)&x[e][128 + q*4] = sv;
    }
    __syncthreads();

    const int l = tid & 63, w = tid >> 6;
    const int l16 = l & 15, quad = l >> 4;
    const int nt0 = 2*w, nt1 = 2*w + 1;
    const int c0 = nt0*16 + l16, c1c = nt1*16 + l16;

    {
        f4 acc[4][2];
        #pragma unroll
        for (int mt = 0; mt < 4; ++mt) { acc[mt][0] = (f4)0.f; acc[mt][1] = (f4)0.f; }
        #pragma unroll
        for (int kc = 0; kc < 8; ++kc) {
            s8 b0  = *(const s8*)(w1p + (((size_t)nt0*8 + kc)*64 + l)*8);
            s8 b1f = *(const s8*)(w1p + (((size_t)nt1*8 + kc)*64 + l)*8);
            #pragma unroll
            for (int mt = 0; mt < 4; ++mt) {
                s8 a = *(const s8*)&x[mt*16 + l16][kc*32 + quad*8];
                acc[mt][0] = __builtin_amdgcn_mfma_f32_16x16x32_bf16(a, b0,  acc[mt][0], 0, 0, 0);
                acc[mt][1] = __builtin_amdgcn_mfma_f32_16x16x32_bf16(a, b1f, acc[mt][1], 0, 0, 0);
            }
        }
        float bia0 = b1n[c0], bia1 = b1n[c1c];
        #pragma unroll
        for (int mt = 0; mt < 4; ++mt) {
            #pragma unroll
            for (int i = 0; i < 4; ++i) {
                int row = mt*16 + quad*4 + i;
                t1[row][c0]  = f2b(siluf(acc[mt][0][i] + bia0));
                t1[row][c1c] = f2b(siluf(acc[mt][1][i] + bia1));
            }
        }
    }
    __syncthreads();

    {
        f4 acc[4][2];
        #pragma unroll
        for (int mt = 0; mt < 4; ++mt) { acc[mt][0] = (f4)0.f; acc[mt][1] = (f4)0.f; }
        #pragma unroll
        for (int kc = 0; kc < 4; ++kc) {
            s8 b0  = *(const s8*)(w2p + (((size_t)nt0*4 + kc)*64 + l)*8);
            s8 b1f = *(const s8*)(w2p + (((size_t)nt1*4 + kc)*64 + l)*8);
            #pragma unroll
            for (int mt = 0; mt < 4; ++mt) {
                s8 a = *(const s8*)&t1[mt*16 + l16][kc*32 + quad*8];
                acc[mt][0] = __builtin_amdgcn_mfma_f32_16x16x32_bf16(a, b0,  acc[mt][0], 0, 0, 0);
                acc[mt][1] = __builtin_amdgcn_mfma_f32_16x16x32_bf16(a, b1f, acc[mt][1], 0, 0, 0);
            }
        }
        float bia0 = b2n[c0], bia1 = b2n[c1c];
        __syncthreads();
        #pragma unroll
        for (int mt = 0; mt < 4; ++mt) {
            #pragma unroll
            for (int i = 0; i < 4; ++i) {
                int row = mt*16 + quad*4 + i;
                hn[row][c0]  = acc[mt][0][i] + bia0;
                hn[row][c1c] = acc[mt][1][i] + bia1;
            }
        }
    }
    __syncthreads();

    {
        int r = tid >> 2, part = tid & 3;
        float s = 0.f, q = 0.f;
        #pragma unroll
        for (int j = 0; j < 32; ++j) {
            float v = hn[r][part + 4*j];
            s += v; q += v*v;
        }
        s += __shfl_xor(s, 1); q += __shfl_xor(q, 1);
        s += __shfl_xor(s, 2); q += __shfl_xor(q, 2);
        if (part == 0) {
            float mu = s * (1.0f/HID);
            float var = q * (1.0f/HID) - mu*mu;
            mus[r] = mu;
            rstds[r] = rsqrtf(var + 1e-5f);
        }
    }
    __syncthreads();

    #pragma unroll
    for (int it = 0; it < 32; ++it) {
        int idx = it*256 + tid;
        int r = idx >> 7, c = idx & 127;
        float v = (hn[r][c] - mus[r]) * rstds[r] * lg[c] + lb[c];
        long o = (long)(n0 + r)*HID + c;
        h[o] = v;
        hb[o] = f2b(v);
    }
    if (tid < 192) {
        int i = tid / 3, d = tid - i*3;
        int n = n0 + i;
        float dg = (float)(rowStart[n+1] - rowStart[n]);
        pos[n*3+d] += upd[n*3+d] / (dg + 1e-6f);
    }
}

// ---------------------------------------------------------------------------
__global__ void k_head(const float* __restrict__ h, const float* __restrict__ pos,
                       const float* __restrict__ w1, const float* __restrict__ b1,
                       const float* __restrict__ w2, const float* __restrict__ b2,
                       void* __restrict__ out, const int* __restrict__ flags)
{
    __shared__ float hs[4][HID];
    __shared__ float t[4][64];
    const int tid = threadIdx.x;
    const int n0 = blockIdx.x * 4;
    for (int i = tid; i < 4*HID; i += 256) hs[i >> 7][i & 127] = h[(long)n0*HID + i];
    __syncthreads();
    const int s = tid >> 6, c = tid & 63;
    float acc = b1[c];
    for (int k4 = 0; k4 < 32; ++k4) {
        int k = k4*4;
        float wa = w1[(k+0)*64 + c];
        float wb = w1[(k+1)*64 + c];
        float wc = w1[(k+2)*64 + c];
        float wd = w1[(k+3)*64 + c];
        float4 v = *(const float4*)&hs[s][k];
        acc += v.x*wa + v.y*wb + v.z*wc + v.w*wd;
    }
    t[s][c] = siluf(acc);
    __syncthreads();
    if (c < 3) {
        float a2 = b2[c];
        #pragma unroll
        for (int k = 0; k < 64; ++k) a2 += t[s][k] * w2[k*3 + c];
        int n = n0 + s;
        float v = pos[n*3+c] + a2;
        if (flags[0]) ((__hip_bfloat16*)out)[n*3+c] = __float2bfloat16(v);
        else          ((float*)out)[n*3+c] = v;
    }
}

// ---------------------------------------------------------------------------
extern "C" void kernel_launch(void* const* d_in, const int* in_sizes, int n_in,
                              void* d_out, int out_size, void* d_ws, size_t ws_size,
                              hipStream_t stream)
{
    (void)in_sizes; (void)n_in; (void)out_size; (void)ws_size;

    int* flags = (int*)d_ws;
    float* base = (float*)d_ws;
    size_t off = 64;
    auto alloc = [&](size_t n) { float* p = base + off; off += (n + 63) & ~63ull; return p; };

    static const int aidx[24] = {0,1,3,4,5,6,7,8,9,10,11,12,13,14,15,16,17,18,19,20,21,22,23,24};
    static const int alen[24] = {
        BB*LAT, NN*AF, NA*3, LAT*HID, HID, AF*HID, HID,
        NL*257*HID, NL*HID, NL*HID*HID, NL*HID,
        NL*256*HID, NL*HID, NL*HID*HID, NL*HID,
        NL*HID*HID, NL*HID, NL*HID, NL*HID, NL*HID,
        HID*64, 64, 64*3, 3
    };
    CvtDesc cd;
    float* fp[24];
    for (int a = 0; a < 24; ++a) {
        fp[a] = alloc((size_t)alen[a]);
        cd.src[a] = d_in[aidx[a]];
        cd.dst[a] = fp[a];
        cd.len[a] = alen[a];
    }
    float* h   = alloc((size_t)NN*HID);
    float* agg = alloc((size_t)NN*HID);
    float* hz  = alloc((size_t)BB*HID);
    float* pos = alloc((size_t)NN*3);
    float* upd = alloc((size_t)NN*3);
    short* hb  = (short*)alloc((size_t)NN*HID/2);
    short* w1p = (short*)alloc((size_t)NL*32768/2);
    short* w2p = (short*)alloc((size_t)NL*16384/2);
    short* c1p = (short*)alloc((size_t)NL*16384/2);
    short* nw1p = (short*)alloc((size_t)NL*32768/2);
    short* nw2p = (short*)alloc((size_t)NL*16384/2);
    int* cnt      = (int*)alloc((size_t)NN);
    int* rowStart = (int*)alloc((size_t)NN + 1);
    int* cursor   = (int*)alloc((size_t)NN);
    int* rS       = (int*)alloc((size_t)NE);
    int* cS       = (int*)alloc((size_t)NE);
    const int* eidx = (const int*)d_in[2];

    k_detect<<<1, 256, 0, stream>>>((const unsigned short*)d_in[0],
                                    (const unsigned int*)d_in[2], flags);
    k_convert<<<dim3((NN*AF + 255)/256, 24), 256, 0, stream>>>(cd, flags);

    for (int l = 0; l < NL; ++l) {
        k_pack<<<128, 256, 0, stream>>>(fp[7]  + (size_t)l*257*HID, w1p  + (size_t)l*32768, 256);
        k_pack<<<64,  256, 0, stream>>>(fp[9]  + (size_t)l*HID*HID, w2p  + (size_t)l*16384, 128);
        k_pack<<<64,  256, 0, stream>>>(fp[15] + (size_t)l*HID*HID, c1p  + (size_t)l*16384, 128);
        k_pack<<<128, 256, 0, stream>>>(fp[11] + (size_t)l*256*HID, nw1p + (size_t)l*32768, 256);
        k_pack<<<64,  256, 0, stream>>>(fp[13] + (size_t)l*HID*HID, nw2p + (size_t)l*16384, 128);
    }

    // counting sort edges by row
    k_zero_cnt<<<(NN + 255)/256, 256, 0, stream>>>(cnt);
    k_hist<<<(NE + 255)/256, 256, 0, stream>>>(eidx, flags, cnt);
    k_scan<<<1, 1024, 0, stream>>>(cnt, rowStart, cursor);
    k_scatter<<<(NE + 255)/256, 256, 0, stream>>>(eidx, flags, cursor, rS, cS);

    k_hz<<<BB, HID, 0, stream>>>(fp[0], fp[3], fp[4], hz);
    k_init_h<<<NN, HID, 0, stream>>>(hz, fp[1], fp[5], fp[6], h);
    k_init_pos<<<(NN*3 + 255)/256, 256, 0, stream>>>(fp[2], pos);
    k_h2b<<<(NN*HID + 255)/256, 256, 0, stream>>>(h, hb);

    for (int l = 0; l < NL; ++l) {
        k_zero<<<(NN*HID + 255)/256, 256, 0, stream>>>(agg, upd);
        k_edge_mfma<<<PBLK, 256, 0, stream>>>(hb, pos, rS, cS,
            w1p + (size_t)l*32768,
            fp[7] + (size_t)l*257*HID + 256*HID,
            fp[8] + (size_t)l*HID,
            w2p + (size_t)l*16384, fp[10] + (size_t)l*HID,
            c1p + (size_t)l*16384, fp[16] + (size_t)l*HID,
            fp[17] + (size_t)l*HID,
            agg, upd);
        k_node_mfma<<<NN/64, 256, 0, stream>>>(h, hb, agg,
            nw1p + (size_t)l*32768, fp[12] + (size_t)l*HID,
            nw2p + (size_t)l*16384, fp[14] + (size_t)l*HID,
            fp[18] + (size_t)l*HID, fp[19] + (size_t)l*HID,
            pos, upd, rowStart);
    }
    k_head<<<NN/4, 256, 0, stream>>>(h, pos, fp[20], fp[21], fp[22], fp[23],
                                     d_out, flags);
}

// Round 5
// 720.888 us; speedup vs baseline: 4.7082x; 1.2557x over previous
//
#include <hip/hip_runtime.h>
#include <hip/hip_bf16.h>

#define BB 512
#define NA 58
#define LAT 64
#define HID 128
#define AF 10
#define NL 2
#define NN (BB*NA)      // 29696
#define NE (NN*16)      // 475136
#define ET 64           // edges per MFMA tile
#define NTILE (NE/ET)   // 7424
#define PBLK 768        // persistent blocks (3 per CU)

typedef __attribute__((ext_vector_type(8))) short s8;
typedef __attribute__((ext_vector_type(4))) float f4;

struct CvtDesc {
    const void* src[24];
    float*      dst[24];
    int         len[24];
};

__device__ __forceinline__ float siluf(float x) {
    return x / (1.0f + __expf(-x));
}

__device__ __forceinline__ short f2b(float x) {
    __hip_bfloat16 b = __float2bfloat16(x);
    return *(short*)&b;
}

__device__ __forceinline__ float b2f(short s) {
    return __uint_as_float(((unsigned int)(unsigned short)s) << 16);
}

// ---------------------------------------------------------------------------
__global__ void k_detect(const unsigned short* __restrict__ z16,
                         const unsigned int* __restrict__ e32,
                         int* __restrict__ flags) {
    __shared__ int sbf, si64;
    if (threadIdx.x == 0) { sbf = 0; si64 = 0; }
    __syncthreads();
    int c1 = 0, c2 = 0;
    for (int i = threadIdx.x; i < 1024; i += 256) {
        unsigned short v = z16[2*i];
        int e = (v >> 7) & 0xFF;
        if (e >= 100 && e <= 140) c1++;
        if (e32[2*i + 1] == 0u) c2++;
    }
    atomicAdd(&sbf, c1);
    atomicAdd(&si64, c2);
    __syncthreads();
    if (threadIdx.x == 0) {
        flags[0] = (sbf  > 600) ? 1 : 0;
        flags[1] = (si64 > 600) ? 1 : 0;
    }
}

__global__ void k_convert(CvtDesc d, const int* __restrict__ flags) {
    int a = blockIdx.y;
    int i = blockIdx.x * blockDim.x + threadIdx.x;
    int n = d.len[a];
    if (i >= n) return;
    if (flags[0]) {
        d.dst[a][i] = __bfloat162float(((const __hip_bfloat16*)d.src[a])[i]);
    } else {
        d.dst[a][i] = ((const float*)d.src[a])[i];
    }
}

// Pack f32 weight [K][128] into bf16 B-fragment order
__global__ void k_pack(const float* __restrict__ w, short* __restrict__ o, int K) {
    int idx = blockIdx.x * 256 + threadIdx.x;
    int total = 128 * K;
    if (idx >= total) return;
    int j  = idx & 7;
    int l  = (idx >> 3) & 63;
    int rest = idx >> 9;
    int KC = K >> 5;
    int kc = rest % KC;
    int nt = rest / KC;
    int n = nt*16 + (l & 15);
    int k = kc*32 + (l >> 4)*8 + j;
    o[idx] = f2b(w[k*128 + n]);
}

// Pack edge_w1 (257x128) rows 0..255 as a K=128, N=256 B-fragment tensor:
// Wcat[k][n] = n<128 ? w1[k][n] : w1[128+k][n-128]
__global__ void k_pack2(const float* __restrict__ ew1, short* __restrict__ o) {
    int idx = blockIdx.x * 256 + threadIdx.x;     // 32768 total
    if (idx >= 32768) return;
    int j  = idx & 7;
    int l  = (idx >> 3) & 63;
    int rest = idx >> 9;
    int kc = rest & 3;        // KC = 4 (K=128)
    int nt = rest >> 2;       // 0..15
    int n = nt*16 + (l & 15);
    int k = kc*32 + (l >> 4)*8 + j;
    float v = (n < 128) ? ew1[k*128 + n] : ew1[(128 + k)*128 + (n - 128)];
    o[idx] = f2b(v);
}

__global__ void k_h2b(const float* __restrict__ h, short* __restrict__ hb) {
    int i = blockIdx.x * 256 + threadIdx.x;
    if (i < NN*HID) hb[i] = f2b(h[i]);
}

// ---------------------------------------------------------------------------
// counting sort of edges by row
__global__ void k_zero_cnt(int* __restrict__ cnt) {
    int i = blockIdx.x * 256 + threadIdx.x;
    if (i < NN) cnt[i] = 0;
}

__global__ void k_hist(const int* __restrict__ eidx, const int* __restrict__ flags,
                       int* __restrict__ cnt) {
    int e = blockIdx.x * 256 + threadIdx.x;
    if (e >= NE) return;
    int is64 = flags[1];
    int r = eidx[is64 ? 2*(long)e : (long)e];
    atomicAdd(&cnt[r], 1);
}

__global__ __launch_bounds__(1024) void k_scan(const int* __restrict__ cnt,
                                               int* __restrict__ rowStart,
                                               int* __restrict__ cursor) {
    __shared__ int part[1024];
    int t = threadIdx.x;
    int base = t * 29;                    // NN == 1024*29
    int loc[29];
    int s = 0;
    #pragma unroll
    for (int i = 0; i < 29; ++i) { loc[i] = s; s += cnt[base + i]; }
    part[t] = s;
    __syncthreads();
    for (int d = 1; d < 1024; d <<= 1) {
        int v = (t >= d) ? part[t - d] : 0;
        __syncthreads();
        part[t] += v;
        __syncthreads();
    }
    int pre = (t == 0) ? 0 : part[t - 1];
    #pragma unroll
    for (int i = 0; i < 29; ++i) {
        int v = pre + loc[i];
        rowStart[base + i] = v;
        cursor[base + i] = v;
    }
    if (t == 1023) rowStart[NN] = pre + s;
}

__global__ void k_scatter(const int* __restrict__ eidx, const int* __restrict__ flags,
                          int* __restrict__ cursor,
                          int* __restrict__ rS, int* __restrict__ cS) {
    int e = blockIdx.x * 256 + threadIdx.x;
    if (e >= NE) return;
    int is64 = flags[1];
    long ge = e, gc = (long)e + NE;
    int r = eidx[is64 ? 2*ge : ge];
    int c = eidx[is64 ? 2*gc : gc];
    int p = atomicAdd(&cursor[r], 1);
    rS[p] = r; cS[p] = c;
}

// ---------------------------------------------------------------------------
__global__ void k_hz(const float* __restrict__ z, const float* __restrict__ lw,
                     const float* __restrict__ lb, float* __restrict__ hz) {
    __shared__ float zs[LAT];
    int b = blockIdx.x;
    int c = threadIdx.x;
    if (c < LAT) zs[c] = z[b*LAT + c];
    __syncthreads();
    float acc = lb[c];
    #pragma unroll
    for (int k = 0; k < LAT; ++k) acc += zs[k] * lw[k*HID + c];
    hz[b*HID + c] = acc;
}

__global__ void k_init_h(const float* __restrict__ hz, const float* __restrict__ at,
                         const float* __restrict__ aw, const float* __restrict__ ab,
                         float* __restrict__ h) {
    __shared__ float ats[AF];
    int n = blockIdx.x;
    int c = threadIdx.x;
    int b = n / NA;
    if (c < AF) ats[c] = at[n*AF + c];
    __syncthreads();
    float acc = hz[b*HID + c] + ab[c];
    #pragma unroll
    for (int f = 0; f < AF; ++f) acc += ats[f] * aw[f*HID + c];
    h[(long)n*HID + c] = acc;
}

__global__ void k_init_pos(const float* __restrict__ ic, float* __restrict__ pos) {
    int i = blockIdx.x * blockDim.x + threadIdx.x;
    if (i >= NN*3) return;
    int n = i / 3, d = i - n*3;
    int a = n % NA;
    pos[i] = ic[a*3 + d];
}

__global__ void k_zero(float* __restrict__ agg, float* __restrict__ upd) {
    int i = blockIdx.x * blockDim.x + threadIdx.x;
    if (i < NN*HID) agg[i] = 0.f;
    if (i < NN*3)   upd[i] = 0.f;
}

// ---------------------------------------------------------------------------
// H1 = hb @ [w1a|w1b]  -> [NN][256] bf16.  64 rows/block, 4 waves x 64 cols.
__global__ __launch_bounds__(256) void k_pre(
    const short* __restrict__ hb, const short* __restrict__ wcat,
    short* __restrict__ H1)
{
    __shared__ short x[64][136];
    const int tid = threadIdx.x;
    const int n0 = blockIdx.x * 64;

    #pragma unroll
    for (int it = 0; it < 4; ++it) {
        int idx = it*256 + tid;
        int e = idx >> 4, q = idx & 15;
        *(int4*)&x[e][q*8] = *(const int4*)(hb + (long)(n0+e)*HID + q*8);
    }
    __syncthreads();

    const int l = tid & 63, w = tid >> 6;
    const int l16 = l & 15, quad = l >> 4;

    f4 acc[4][4];
    #pragma unroll
    for (int mt = 0; mt < 4; ++mt)
        #pragma unroll
        for (int nt4 = 0; nt4 < 4; ++nt4) acc[mt][nt4] = (f4)0.f;

    #pragma unroll
    for (int kc = 0; kc < 4; ++kc) {
        s8 a[4];
        #pragma unroll
        for (int mt = 0; mt < 4; ++mt)
            a[mt] = *(const s8*)&x[mt*16 + l16][kc*32 + quad*8];
        #pragma unroll
        for (int nt4 = 0; nt4 < 4; ++nt4) {
            int nt = w*4 + nt4;
            s8 b = *(const s8*)(wcat + (((size_t)nt*4 + kc)*64 + l)*8);
            #pragma unroll
            for (int mt = 0; mt < 4; ++mt)
                acc[mt][nt4] = __builtin_amdgcn_mfma_f32_16x16x32_bf16(a[mt], b, acc[mt][nt4], 0, 0, 0);
        }
    }
    #pragma unroll
    for (int mt = 0; mt < 4; ++mt)
        #pragma unroll
        for (int nt4 = 0; nt4 < 4; ++nt4)
            #pragma unroll
            for (int i = 0; i < 4; ++i) {
                int row = mt*16 + quad*4 + i;
                int col = (w*4 + nt4)*16 + l16;
                H1[(long)(n0 + row)*256 + col] = f2b(acc[mt][nt4][i]);
            }
}

// ---------------------------------------------------------------------------
// Edge kernel: stage1 is elementwise (H1 gathers), stages 2-3 MFMA.
#define PREMETA(T) do {                                                       \
    long eb = (long)(T) * ET;                                                 \
    if (tid < ET) {                                                           \
        pr_r = rS[eb + tid];                                                  \
        pr_c = cS[eb + tid];                                                  \
        float rx = pos[pr_r*3+0] - pos[pr_c*3+0];                             \
        float ry = pos[pr_r*3+1] - pos[pr_c*3+1];                             \
        float rz = pos[pr_r*3+2] - pos[pr_c*3+2];                             \
        pr_rel0 = rx; pr_rel1 = ry; pr_rel2 = rz;                             \
        pr_d2 = fminf(fmaxf(rx*rx + ry*ry + rz*rz, 1e-6f), 1e6f);             \
    }                                                                         \
} while (0)

__global__ __launch_bounds__(256, 3) void k_edge2(
    const short* __restrict__ H1, const float* __restrict__ pos,
    const int* __restrict__ rS, const int* __restrict__ cS,
    const float* __restrict__ w1c, const float* __restrict__ b1,
    const short* __restrict__ w2p, const float* __restrict__ b2,
    const short* __restrict__ c1p, const float* __restrict__ cb1,
    const float* __restrict__ cw2,
    float* __restrict__ agg, float* __restrict__ upd)
{
    __shared__ short t1[ET][136];
    __shared__ short mm[ET][136];
    __shared__ int   rIs[ET], cIs[ET];
    __shared__ float relS[ET][3];
    __shared__ float d2s[ET];
    __shared__ float sred[ET];
    __shared__ float w1cS[HID], b1S[HID];

    const int tid = threadIdx.x;
    const int l = tid & 63, w = tid >> 6;
    const int l16 = l & 15, quad = l >> 4;
    const int c0 = (2*w)*16 + l16, c1c = (2*w+1)*16 + l16;
    const int half = tid >> 7, ch = tid & 127;

    if (tid < HID) { w1cS[tid] = w1c[tid]; b1S[tid] = b1[tid]; }

    s8 w2f[8], c1f[8];
    #pragma unroll
    for (int kc = 0; kc < 4; ++kc) {
        w2f[kc]     = *(const s8*)(w2p + (((size_t)(2*w)*4 + kc)*64 + l)*8);
        w2f[4 + kc] = *(const s8*)(w2p + (((size_t)(2*w+1)*4 + kc)*64 + l)*8);
        c1f[kc]     = *(const s8*)(c1p + (((size_t)(2*w)*4 + kc)*64 + l)*8);
        c1f[4 + kc] = *(const s8*)(c1p + (((size_t)(2*w+1)*4 + kc)*64 + l)*8);
    }
    const float bia2_0 = b2[c0],  bia2_1 = b2[c1c];
    const float biac_0 = cb1[c0], biac_1 = cb1[c1c];
    const float cw0    = cw2[c0], cw1v   = cw2[c1c];

    int pr_r = 0, pr_c = 0;
    float pr_rel0 = 0.f, pr_rel1 = 0.f, pr_rel2 = 0.f, pr_d2 = 0.f;

    int t = blockIdx.x;
    if (t < NTILE) PREMETA(t);

    while (t < NTILE) {
        __syncthreads();                       // (1) prior tile fully consumed
        if (tid < ET) {
            rIs[tid] = pr_r; cIs[tid] = pr_c;
            relS[tid][0] = pr_rel0; relS[tid][1] = pr_rel1; relS[tid][2] = pr_rel2;
            d2s[tid] = pr_d2;
            sred[tid] = 0.f;
        }
        __syncthreads();                       // (2) meta visible

        // ---- build t1 = silu(H1a[row] + H1b[col] + d2*w1c + b1)
        #pragma unroll
        for (int it = 0; it < 4; ++it) {
            int idx = it*256 + tid;
            int e = idx >> 4, q = idx & 15;
            int ri = rIs[e], ci = cIs[e];
            float d2 = d2s[e];
            int4 va = *(const int4*)(H1 + (long)ri*256 + q*8);
            int4 vb = *(const int4*)(H1 + (long)ci*256 + 128 + q*8);
            const short* sa = (const short*)&va;
            const short* sb = (const short*)&vb;
            short o[8];
            #pragma unroll
            for (int j = 0; j < 8; ++j) {
                int cc = q*8 + j;
                float v = b2f(sa[j]) + b2f(sb[j]) + d2*w1cS[cc] + b1S[cc];
                o[j] = f2b(siluf(v));
            }
            *(int4*)&t1[e][q*8] = *(int4*)o;
        }
        int tn = t + PBLK;
        if (tn < NTILE) PREMETA(tn);
        __syncthreads();                       // (3) t1 complete

        // ---- stage 2: m = silu(t1 @ w2 + b2) -> mm bf16
        {
            f4 acc[4][2];
            #pragma unroll
            for (int mt = 0; mt < 4; ++mt) { acc[mt][0] = (f4)0.f; acc[mt][1] = (f4)0.f; }
            #pragma unroll
            for (int kc = 0; kc < 4; ++kc) {
                #pragma unroll
                for (int mt = 0; mt < 4; ++mt) {
                    s8 a = *(const s8*)&t1[mt*16 + l16][kc*32 + quad*8];
                    acc[mt][0] = __builtin_amdgcn_mfma_f32_16x16x32_bf16(a, w2f[kc],     acc[mt][0], 0, 0, 0);
                    acc[mt][1] = __builtin_amdgcn_mfma_f32_16x16x32_bf16(a, w2f[4 + kc], acc[mt][1], 0, 0, 0);
                }
            }
            #pragma unroll
            for (int mt = 0; mt < 4; ++mt) {
                #pragma unroll
                for (int i = 0; i < 4; ++i) {
                    int row = mt*16 + quad*4 + i;
                    mm[row][c0]  = f2b(siluf(acc[mt][0][i] + bia2_0));
                    mm[row][c1c] = f2b(siluf(acc[mt][1][i] + bia2_1));
                }
            }
        }
        __syncthreads();                       // (4) mm complete

        // ---- stage 3: c1 = silu(mm @ cw1 + cb1); dot cw2 -> sred
        {
            f4 acc[4][2];
            #pragma unroll
            for (int mt = 0; mt < 4; ++mt) { acc[mt][0] = (f4)0.f; acc[mt][1] = (f4)0.f; }
            #pragma unroll
            for (int kc = 0; kc < 4; ++kc) {
                #pragma unroll
                for (int mt = 0; mt < 4; ++mt) {
                    s8 a = *(const s8*)&mm[mt*16 + l16][kc*32 + quad*8];
                    acc[mt][0] = __builtin_amdgcn_mfma_f32_16x16x32_bf16(a, c1f[kc],     acc[mt][0], 0, 0, 0);
                    acc[mt][1] = __builtin_amdgcn_mfma_f32_16x16x32_bf16(a, c1f[4 + kc], acc[mt][1], 0, 0, 0);
                }
            }
            #pragma unroll
            for (int mt = 0; mt < 4; ++mt) {
                #pragma unroll
                for (int i = 0; i < 4; ++i) {
                    float p = siluf(acc[mt][0][i] + biac_0) * cw0
                            + siluf(acc[mt][1][i] + biac_1) * cw1v;
                    p += __shfl_xor(p, 1);
                    p += __shfl_xor(p, 2);
                    p += __shfl_xor(p, 4);
                    p += __shfl_xor(p, 8);
                    if (l16 == 0) {
                        int row = mt*16 + quad*4 + i;
                        atomicAdd(&sred[row], p);
                    }
                }
            }
        }

        // ---- segmented agg reduction over sorted rows (reads mm bf16)
        {
            int e0 = half * 32;
            int cur = rIs[e0];
            float a = 0.f;
            #pragma unroll
            for (int e = e0; e < e0 + 32; ++e) {
                int r = rIs[e];
                if (r != cur) {
                    atomicAdd(&agg[(long)cur*HID + ch], a);
                    a = 0.f; cur = r;
                }
                a += b2f(mm[e][ch]);
            }
            atomicAdd(&agg[(long)cur*HID + ch], a);
        }
        __syncthreads();                       // (5) sred complete

        if (tid < ET) {
            float cwv = fminf(fmaxf(sred[tid], -1.f), 1.f);
            int r = rIs[tid];
            atomicAdd(&upd[r*3+0], cwv*relS[tid][0]);
            atomicAdd(&upd[r*3+1], cwv*relS[tid][1]);
            atomicAdd(&upd[r*3+2], cwv*relS[tid][2]);
        }
        t = tn;
    }
}

// ---------------------------------------------------------------------------
// MFMA node kernel: 64 nodes/block; x=[h|agg] bf16; LN in f32; writes h + hb.
__global__ __launch_bounds__(256) void k_node_mfma(
    float* __restrict__ h, short* __restrict__ hb, const float* __restrict__ agg,
    const short* __restrict__ w1p, const float* __restrict__ b1n,
    const short* __restrict__ w2p, const float* __restrict__ b2n,
    const float* __restrict__ lg, const float* __restrict__ lb,
    float* __restrict__ pos, const float* __restrict__ upd,
    const int* __restrict__ rowStart)
{
    __shared__ short x[64][264];
    __shared__ short t1[64][144];
    __shared__ float mus[64], rstds[64];
    float (*hn)[132] = (float (*)[132])&x[0][0];

    const int tid = threadIdx.x;
    const int n0 = blockIdx.x * 64;

    #pragma unroll
    for (int it = 0; it < 4; ++it) {
        int idx = it*256 + tid;
        int e = idx >> 4, q = idx & 15;
        *(int4*)&x[e][q*8] = *(const int4*)(hb + (long)(n0+e)*HID + q*8);
    }
    #pragma unroll
    for (int it = 0; it < 8; ++it) {
        int idx = it*256 + tid;
        int e = idx >> 5, q = idx & 31;
        float4 v = *(const float4*)(agg + (long)(n0+e)*HID + q*4);
        short4 sv;
        sv.x = f2b(v.x); sv.y = f2b(v.y); sv.z = f2b(v.z); sv.w = f2b(v.w);
        *(short4*)&x[e][128 + q*4] = sv;
    }
    __syncthreads();

    const int l = tid & 63, w = tid >> 6;
    const int l16 = l & 15, quad = l >> 4;
    const int nt0 = 2*w, nt1 = 2*w + 1;
    const int c0 = nt0*16 + l16, c1c = nt1*16 + l16;

    {
        f4 acc[4][2];
        #pragma unroll
        for (int mt = 0; mt < 4; ++mt) { acc[mt][0] = (f4)0.f; acc[mt][1] = (f4)0.f; }
        #pragma unroll
        for (int kc = 0; kc < 8; ++kc) {
            s8 b0  = *(const s8*)(w1p + (((size_t)nt0*8 + kc)*64 + l)*8);
            s8 b1f = *(const s8*)(w1p + (((size_t)nt1*8 + kc)*64 + l)*8);
            #pragma unroll
            for (int mt = 0; mt < 4; ++mt) {
                s8 a = *(const s8*)&x[mt*16 + l16][kc*32 + quad*8];
                acc[mt][0] = __builtin_amdgcn_mfma_f32_16x16x32_bf16(a, b0,  acc[mt][0], 0, 0, 0);
                acc[mt][1] = __builtin_amdgcn_mfma_f32_16x16x32_bf16(a, b1f, acc[mt][1], 0, 0, 0);
            }
        }
        float bia0 = b1n[c0], bia1 = b1n[c1c];
        #pragma unroll
        for (int mt = 0; mt < 4; ++mt) {
            #pragma unroll
            for (int i = 0; i < 4; ++i) {
                int row = mt*16 + quad*4 + i;
                t1[row][c0]  = f2b(siluf(acc[mt][0][i] + bia0));
                t1[row][c1c] = f2b(siluf(acc[mt][1][i] + bia1));
            }
        }
    }
    __syncthreads();

    {
        f4 acc[4][2];
        #pragma unroll
        for (int mt = 0; mt < 4; ++mt) { acc[mt][0] = (f4)0.f; acc[mt][1] = (f4)0.f; }
        #pragma unroll
        for (int kc = 0; kc < 4; ++kc) {
            s8 b0  = *(const s8*)(w2p + (((size_t)nt0*4 + kc)*64 + l)*8);
            s8 b1f = *(const s8*)(w2p + (((size_t)nt1*4 + kc)*64 + l)*8);
            #pragma unroll
            for (int mt = 0; mt < 4; ++mt) {
                s8 a = *(const s8*)&t1[mt*16 + l16][kc*32 + quad*8];
                acc[mt][0] = __builtin_amdgcn_mfma_f32_16x16x32_bf16(a, b0,  acc[mt][0], 0, 0, 0);
                acc[mt][1] = __builtin_amdgcn_mfma_f32_16x16x32_bf16(a, b1f, acc[mt][1], 0, 0, 0);
            }
        }
        float bia0 = b2n[c0], bia1 = b2n[c1c];
        __syncthreads();
        #pragma unroll
        for (int mt = 0; mt < 4; ++mt) {
            #pragma unroll
            for (int i = 0; i < 4; ++i) {
                int row = mt*16 + quad*4 + i;
                hn[row][c0]  = acc[mt][0][i] + bia0;
                hn[row][c1c] = acc[mt][1][i] + bia1;
            }
        }
    }
    __syncthreads();

    {
        int r = tid >> 2, part = tid & 3;
        float s = 0.f, q = 0.f;
        #pragma unroll
        for (int j = 0; j < 32; ++j) {
            float v = hn[r][part + 4*j];
            s += v; q += v*v;
        }
        s += __shfl_xor(s, 1); q += __shfl_xor(q, 1);
        s += __shfl_xor(s, 2); q += __shfl_xor(q, 2);
        if (part == 0) {
            float mu = s * (1.0f/HID);
            float var = q * (1.0f/HID) - mu*mu;
            mus[r] = mu;
            rstds[r] = rsqrtf(var + 1e-5f);
        }
    }
    __syncthreads();

    #pragma unroll
    for (int it = 0; it < 32; ++it) {
        int idx = it*256 + tid;
        int r = idx >> 7, c = idx & 127;
        float v = (hn[r][c] - mus[r]) * rstds[r] * lg[c] + lb[c];
        long o = (long)(n0 + r)*HID + c;
        h[o] = v;
        hb[o] = f2b(v);
    }
    if (tid < 192) {
        int i = tid / 3, d = tid - i*3;
        int n = n0 + i;
        float dg = (float)(rowStart[n+1] - rowStart[n]);
        pos[n*3+d] += upd[n*3+d] / (dg + 1e-6f);
    }
}

// ---------------------------------------------------------------------------
__global__ void k_head(const float* __restrict__ h, const float* __restrict__ pos,
                       const float* __restrict__ w1, const float* __restrict__ b1,
                       const float* __restrict__ w2, const float* __restrict__ b2,
                       void* __restrict__ out, const int* __restrict__ flags)
{
    __shared__ float hs[4][HID];
    __shared__ float t[4][64];
    const int tid = threadIdx.x;
    const int n0 = blockIdx.x * 4;
    for (int i = tid; i < 4*HID; i += 256) hs[i >> 7][i & 127] = h[(long)n0*HID + i];
    __syncthreads();
    const int s = tid >> 6, c = tid & 63;
    float acc = b1[c];
    for (int k4 = 0; k4 < 32; ++k4) {
        int k = k4*4;
        float wa = w1[(k+0)*64 + c];
        float wb = w1[(k+1)*64 + c];
        float wc = w1[(k+2)*64 + c];
        float wd = w1[(k+3)*64 + c];
        float4 v = *(const float4*)&hs[s][k];
        acc += v.x*wa + v.y*wb + v.z*wc + v.w*wd;
    }
    t[s][c] = siluf(acc);
    __syncthreads();
    if (c < 3) {
        float a2 = b2[c];
        #pragma unroll
        for (int k = 0; k < 64; ++k) a2 += t[s][k] * w2[k*3 + c];
        int n = n0 + s;
        float v = pos[n*3+c] + a2;
        if (flags[0]) ((__hip_bfloat16*)out)[n*3+c] = __float2bfloat16(v);
        else          ((float*)out)[n*3+c] = v;
    }
}

// ---------------------------------------------------------------------------
extern "C" void kernel_launch(void* const* d_in, const int* in_sizes, int n_in,
                              void* d_out, int out_size, void* d_ws, size_t ws_size,
                              hipStream_t stream)
{
    (void)in_sizes; (void)n_in; (void)out_size; (void)ws_size;

    int* flags = (int*)d_ws;
    float* base = (float*)d_ws;
    size_t off = 64;
    auto alloc = [&](size_t n) { float* p = base + off; off += (n + 63) & ~63ull; return p; };

    static const int aidx[24] = {0,1,3,4,5,6,7,8,9,10,11,12,13,14,15,16,17,18,19,20,21,22,23,24};
    static const int alen[24] = {
        BB*LAT, NN*AF, NA*3, LAT*HID, HID, AF*HID, HID,
        NL*257*HID, NL*HID, NL*HID*HID, NL*HID,
        NL*256*HID, NL*HID, NL*HID*HID, NL*HID,
        NL*HID*HID, NL*HID, NL*HID, NL*HID, NL*HID,
        HID*64, 64, 64*3, 3
    };
    CvtDesc cd;
    float* fp[24];
    for (int a = 0; a < 24; ++a) {
        fp[a] = alloc((size_t)alen[a]);
        cd.src[a] = d_in[aidx[a]];
        cd.dst[a] = fp[a];
        cd.len[a] = alen[a];
    }
    float* h   = alloc((size_t)NN*HID);
    float* agg = alloc((size_t)NN*HID);
    float* hz  = alloc((size_t)BB*HID);
    float* pos = alloc((size_t)NN*3);
    float* upd = alloc((size_t)NN*3);
    short* hb  = (short*)alloc((size_t)NN*HID/2);
    short* H1  = (short*)alloc((size_t)NN*256/2);
    short* wcatp = (short*)alloc((size_t)NL*32768/2);
    short* w2p = (short*)alloc((size_t)NL*16384/2);
    short* c1p = (short*)alloc((size_t)NL*16384/2);
    short* nw1p = (short*)alloc((size_t)NL*32768/2);
    short* nw2p = (short*)alloc((size_t)NL*16384/2);
    int* cnt      = (int*)alloc((size_t)NN);
    int* rowStart = (int*)alloc((size_t)NN + 1);
    int* cursor   = (int*)alloc((size_t)NN);
    int* rS       = (int*)alloc((size_t)NE);
    int* cS       = (int*)alloc((size_t)NE);
    const int* eidx = (const int*)d_in[2];

    k_detect<<<1, 256, 0, stream>>>((const unsigned short*)d_in[0],
                                    (const unsigned int*)d_in[2], flags);
    k_convert<<<dim3((NN*AF + 255)/256, 24), 256, 0, stream>>>(cd, flags);

    for (int l = 0; l < NL; ++l) {
        k_pack2<<<128, 256, 0, stream>>>(fp[7] + (size_t)l*257*HID, wcatp + (size_t)l*32768);
        k_pack<<<64,  256, 0, stream>>>(fp[9]  + (size_t)l*HID*HID, w2p  + (size_t)l*16384, 128);
        k_pack<<<64,  256, 0, stream>>>(fp[15] + (size_t)l*HID*HID, c1p  + (size_t)l*16384, 128);
        k_pack<<<128, 256, 0, stream>>>(fp[11] + (size_t)l*256*HID, nw1p + (size_t)l*32768, 256);
        k_pack<<<64,  256, 0, stream>>>(fp[13] + (size_t)l*HID*HID, nw2p + (size_t)l*16384, 128);
    }

    // counting sort edges by row
    k_zero_cnt<<<(NN + 255)/256, 256, 0, stream>>>(cnt);
    k_hist<<<(NE + 255)/256, 256, 0, stream>>>(eidx, flags, cnt);
    k_scan<<<1, 1024, 0, stream>>>(cnt, rowStart, cursor);
    k_scatter<<<(NE + 255)/256, 256, 0, stream>>>(eidx, flags, cursor, rS, cS);

    k_hz<<<BB, HID, 0, stream>>>(fp[0], fp[3], fp[4], hz);
    k_init_h<<<NN, HID, 0, stream>>>(hz, fp[1], fp[5], fp[6], h);
    k_init_pos<<<(NN*3 + 255)/256, 256, 0, stream>>>(fp[2], pos);
    k_h2b<<<(NN*HID + 255)/256, 256, 0, stream>>>(h, hb);

    for (int l = 0; l < NL; ++l) {
        k_zero<<<(NN*HID + 255)/256, 256, 0, stream>>>(agg, upd);
        k_pre<<<NN/64, 256, 0, stream>>>(hb, wcatp + (size_t)l*32768, H1);
        k_edge2<<<PBLK, 256, 0, stream>>>(H1, pos, rS, cS,
            fp[7] + (size_t)l*257*HID + 256*HID,       // w1c (d2 row, f32)
            fp[8] + (size_t)l*HID,                     // b1
            w2p + (size_t)l*16384, fp[10] + (size_t)l*HID,
            c1p + (size_t)l*16384, fp[16] + (size_t)l*HID,
            fp[17] + (size_t)l*HID,
            agg, upd);
        k_node_mfma<<<NN/64, 256, 0, stream>>>(h, hb, agg,
            nw1p + (size_t)l*32768, fp[12] + (size_t)l*HID,
            nw2p + (size_t)l*16384, fp[14] + (size_t)l*HID,
            fp[18] + (size_t)l*HID, fp[19] + (size_t)l*HID,
            pos, upd, rowStart);
    }
    k_head<<<NN/4, 256, 0, stream>>>(h, pos, fp[20], fp[21], fp[22], fp[23],
                                     d_out, flags);
}